// Round 9
// baseline (241.629 us; speedup 1.0000x reference)
//
#include <hip/hip_runtime.h>
#include <math.h>

#define NMESH 120
#define NKZ 61            // rfft half-spectrum along z
#define NTOT (120*120*120)
#define ALPHA_C 1.0

#define TILE 12           // mesh cells per tile per dim
#define NTPD 10           // tiles per dim
#define NTILE 1000
#define FP 17             // footprint per dim: TILE + 5
#define FPCELLS (FP*FP*FP)   // 4913
#define FPSTRIDE 4928        // padded tile stride
#define CAP 256              // bucket capacity (Poisson(100): overflow ~1e-40)

#define YCH 12            // y-lines per fft_z block (1200 blocks)
#define XCH 4             // x per fft_y block / ky per fft_x block

// ---- workspace layout (bytes) ----
// [0,24)      : 3 doubles: ek, sum(q), sum(q^2)
// [24,28)     : u32 done-counter for fused finalize      (all zeroed by init)
// [115264, +19712000)  : float buf[1000][4928] tile footprints
// [19827264, +7027200) : float2 C1[x][kz][y]
//    counts + CAP-padded sorted atoms ALIAS the C1 region (dead before fft_z writes C1)
// C2[kz][ky][x] ALIASES buf (buf dead after fft_z)
#define ACC_OFF     0
#define DONE_OFF    24
#define BUF_OFF     115264
#define C1_OFF      19827264
#define C2_OFF      115264
#define COUNTS_OFF  C1_OFF
#define SORTED_OFF  (C1_OFF + 4096)      // 1000*256*16 = 4.096 MB < 7 MB region

__device__ inline void inv3(const float* b, float* ib) {
    float a00=b[0],a01=b[1],a02=b[2],a10=b[3],a11=b[4],a12=b[5],a20=b[6],a21=b[7],a22=b[8];
    float c00 =  a11*a22 - a12*a21;
    float c01 = -(a10*a22 - a12*a20);
    float c02 =  a10*a21 - a11*a20;
    float c10 = -(a01*a22 - a02*a21);
    float c11 =  a00*a22 - a02*a20;
    float c12 = -(a00*a21 - a01*a20);
    float c20 =  a01*a12 - a02*a11;
    float c21 = -(a00*a12 - a02*a10);
    float c22 =  a00*a11 - a01*a10;
    float det = a00*c00 + a01*c01 + a02*c02;
    float inv = 1.0f/det;
    ib[0]=c00*inv; ib[1]=c10*inv; ib[2]=c20*inv;
    ib[3]=c01*inv; ib[4]=c11*inv; ib[5]=c21*inv;
    ib[6]=c02*inv; ib[7]=c12*inv; ib[8]=c22*inv;
}

__device__ inline void atom_pos(const float* __restrict__ box, float c0, float c1, float c2,
                                float* p) {
    float ib[9]; inv3(box, ib);
    #pragma unroll
    for (int d=0; d<3; ++d)
        p[d] = (c0*ib[0+d] + c1*ib[3+d] + c2*ib[6+d]) * 120.0f;
}

__device__ inline int wrap120(int i) { return ((i % 120) + 120) % 120; }

// order-6 Lagrange weights; x = pos - (floor(pos)+0.5)
__device__ inline void lag6(float x, float* w) {
    float df[6];
    #pragma unroll
    for (int k=0;k<6;++k) df[k] = x - ((float)k - 2.5f);
    w[0] = df[1]*df[2]*df[3]*df[4]*df[5] * (-1.0f/120.0f);
    w[1] = df[0]*df[2]*df[3]*df[4]*df[5] * ( 1.0f/24.0f);
    w[2] = df[0]*df[1]*df[3]*df[4]*df[5] * (-1.0f/12.0f);
    w[3] = df[0]*df[1]*df[2]*df[4]*df[5] * ( 1.0f/12.0f);
    w[4] = df[0]*df[1]*df[2]*df[3]*df[5] * (-1.0f/24.0f);
    w[5] = df[0]*df[1]*df[2]*df[3]*df[4] * ( 1.0f/120.0f);
}

// per-dim halo decomposition: cell c -> up to 2 (tile, local) pairs
__device__ inline int halo_pairs(int c, int* t, int* l) {
    int r = c % 12, ti = c / 12, n = 0;
    t[n] = ti;          l[n] = r + 2;  n++;
    if (r < 3)  { t[n] = (ti+9)%10; l[n] = r + 14; n++; }
    if (r >= 10){ t[n] = (ti+1)%10; l[n] = r - 10; n++; }
    return n;
}

__global__ void init_kernel(int* __restrict__ counts, double* __restrict__ acc,
                            unsigned* __restrict__ done) {
    int idx = threadIdx.x;
    if (idx < 3) acc[idx] = 0.0;
    if (idx == 3) *done = 0u;
    for (int i = idx; i < NTILE; i += 1024) counts[i] = 0;
}

// one-pass bucket scatter + sum(q) + sum(q^2)
__global__ void scatter_q_kernel(const float* __restrict__ coords,
                                 const float* __restrict__ box,
                                 const float* __restrict__ charges,
                                 int* __restrict__ counts,
                                 float4* __restrict__ sorted,
                                 double* __restrict__ acc, int n) {
    int i = blockIdx.x*blockDim.x + threadIdx.x;
    float v = 0.f, v2 = 0.f;
    if (i < n) {
        float p[3]; atom_pos(box, coords[3*i], coords[3*i+1], coords[3*i+2], p);
        float q = charges[i];
        v = q; v2 = q*q;
        int t[3];
        #pragma unroll
        for (int d=0; d<3; ++d) t[d] = wrap120((int)floorf(p[d])) / TILE;
        int tile = (t[0]*NTPD + t[1])*NTPD + t[2];
        int idx = atomicAdd(&counts[tile], 1);
        if (idx < CAP) sorted[tile*CAP + idx] = make_float4(p[0], p[1], p[2], q);
    }
    #pragma unroll
    for (int o=32;o>0;o>>=1) { v += __shfl_down(v,o,64); v2 += __shfl_down(v2,o,64); }
    __shared__ float s1[4], s2[4];
    int lane = threadIdx.x & 63, w = threadIdx.x >> 6;
    if (lane==0) { s1[w]=v; s2[w]=v2; }
    __syncthreads();
    if (threadIdx.x==0) {
        for (int j=1;j<4;j++) { v += s1[j]; v2 += s2[j]; }
        atomicAdd(&acc[1], (double)v);
        atomicAdd(&acc[2], (double)v2);
    }
}

// TWO WAVES per tile; each wave accumulates its atoms into a private LDS copy
// with plain RMW on exclusively-owned (a,b) slices; merge at flush.
__global__ void __launch_bounds__(128)
spread_tile_kernel(const float4* __restrict__ sorted,
                   const int* __restrict__ counts,
                   float* __restrict__ buf) {
    int tile = blockIdx.x;
    int tx = tile / (NTPD*NTPD);
    int rem = tile - tx*NTPD*NTPD;
    int ty = rem / NTPD;
    int tz = rem - ty*NTPD;
    int bx = tx*TILE, by = ty*TILE, bz = tz*TILE;

    __shared__ float accS[2][FPCELLS];   // 39.3 KB
    __shared__ float W[128][18];         // 9.2 KB
    __shared__ int   baseS[128];

    int tid  = threadIdx.x;
    int wid  = tid >> 6;
    int lane = tid & 63;
    for (int i = tid; i < FPCELLS; i += 128) { accS[0][i] = 0.f; accS[1][i] = 0.f; }

    int a = lane / 6, b = lane - a*6;            // active for lane<36
    int laneoff = a*(FP*FP) + b*FP;

    int cntT = min(counts[tile], CAP);
    const float4* src = sorted + tile*CAP;

    for (int start = 0; start < cntT; start += 128) {
        int my = start + tid;
        if (my < cntT) {
            float4 s = src[my];
            float fx = floorf(s.x);
            float wx[6]; lag6(s.x - (fx + 0.5f), wx);
            float fy = floorf(s.y);
            float wy[6]; lag6(s.y - (fy + 0.5f), wy);
            float fz = floorf(s.z);
            float wz[6]; lag6(s.z - (fz + 0.5f), wz);
            int lx = wrap120((int)fx) - bx;
            int ly = wrap120((int)fy) - by;
            int lz = wrap120((int)fz) - bz;
            baseS[tid] = (lx*FP + ly)*FP + lz;
            #pragma unroll
            for (int k=0;k<6;++k) {
                W[tid][k]    = wx[k]*s.w;
                W[tid][6+k]  = wy[k];
                W[tid][12+k] = wz[k];
            }
        }
        __syncthreads();
        int jn = cntT - start - wid*64;
        jn = (jn > 64) ? 64 : jn;
        if (lane < 36) {
            for (int j = 0; j < jn; ++j) {
                int row = wid*64 + j;
                float w2 = W[row][a] * W[row][6+b];
                int ad = baseS[row] + laneoff;
                #pragma unroll
                for (int c=0;c<6;++c)
                    accS[wid][ad + c] += w2 * W[row][12+c];
            }
        }
        __syncthreads();
    }

    for (int i = tid; i < FPCELLS; i += 128)
        buf[(size_t)tile * FPSTRIDE + i] = accS[0][i] + accS[1][i];
}

// stage 1: halo-gather + rfft along z; twiddles from LDS table, 4 strands.
__global__ void __launch_bounds__(256)
fft_z_kernel(const float* __restrict__ buf,
             float2* __restrict__ C1) {
    int x  = blockIdx.x / 10;
    int y0 = (blockIdx.x - x*10) * YCH;
    __shared__ float  lds[YCH][121];
    __shared__ float2 Tm[120];

    for (int i = threadIdx.x; i < 120; i += 256) {
        double sd, cd; sincos(-2.0*M_PI*(double)i/120.0, &sd, &cd);
        Tm[i] = make_float2((float)cd, (float)sd);
    }

    int txA[2], lxA[2];
    int nx = halo_pairs(x, txA, lxA);

    for (int i = threadIdx.x; i < YCH*120; i += 256) {
        int yl = i / 120, z = i - yl*120;
        int tyA[2], lyA[2]; int ny = halo_pairs(y0 + yl, tyA, lyA);
        int tzA[2], lzA[2]; int nz = halo_pairs(z, tzA, lzA);
        float s = 0.f;
        for (int ii=0; ii<nx; ++ii)
            for (int jj=0; jj<ny; ++jj)
                for (int kk=0; kk<nz; ++kk) {
                    int tile = (txA[ii]*NTPD + tyA[jj])*NTPD + tzA[kk];
                    int cell = (lxA[ii]*FP + lyA[jj])*FP + lzA[kk];
                    s += buf[(size_t)tile*FPSTRIDE + cell];
                }
        lds[yl][z] = s;
    }
    __syncthreads();
    for (int o = threadIdx.x; o < YCH*NKZ; o += 256) {
        int kz = o / YCH, yl = o - kz*YCH;
        int k4  = (4*kz) % 120;
        int id0 = 0, id1 = kz, id2 = (2*kz)%120, id3 = (3*kz)%120;
        float r0=0,r1=0,r2=0,r3=0, i0=0,i1=0,i2=0,i3=0;
        for (int m=0; m<30; ++m) {
            float v0 = lds[yl][4*m+0]; float2 t0 = Tm[id0];
            float v1 = lds[yl][4*m+1]; float2 t1 = Tm[id1];
            float v2 = lds[yl][4*m+2]; float2 t2 = Tm[id2];
            float v3 = lds[yl][4*m+3]; float2 t3 = Tm[id3];
            r0 = fmaf(v0,t0.x,r0); i0 = fmaf(v0,t0.y,i0);
            r1 = fmaf(v1,t1.x,r1); i1 = fmaf(v1,t1.y,i1);
            r2 = fmaf(v2,t2.x,r2); i2 = fmaf(v2,t2.y,i2);
            r3 = fmaf(v3,t3.x,r3); i3 = fmaf(v3,t3.y,i3);
            id0 += k4; id0 -= (id0>=120)?120:0;
            id1 += k4; id1 -= (id1>=120)?120:0;
            id2 += k4; id2 -= (id2>=120)?120:0;
            id3 += k4; id3 -= (id3>=120)?120:0;
        }
        C1[(x*NKZ + kz)*120 + y0 + yl] = make_float2((r0+r1)+(r2+r3), (i0+i1)+(i2+i3));
    }
}

// stage 2: cfft along y; LDS twiddle table. block = (4 consecutive x, kz). out C2[kz][ky][x].
__global__ void __launch_bounds__(256)
fft_y_kernel(const float2* __restrict__ C1,
             float2* __restrict__ C2) {
    int xc = blockIdx.x / NKZ;
    int kz = blockIdx.x - xc*NKZ;
    int x0 = xc * XCH;
    __shared__ float2 lds[XCH][121];
    __shared__ float2 Tm[120];
    for (int i = threadIdx.x; i < 120; i += 256) {
        double sd, cd; sincos(-2.0*M_PI*(double)i/120.0, &sd, &cd);
        Tm[i] = make_float2((float)cd, (float)sd);
    }
    for (int i = threadIdx.x; i < XCH*120; i += 256) {
        int xo = i / 120, y = i - xo*120;
        lds[xo][y] = C1[((x0+xo)*NKZ + kz)*120 + y];
    }
    __syncthreads();
    for (int o = threadIdx.x; o < XCH*120; o += 256) {
        int ky = o >> 2, xo = o & 3;
        int k4  = (4*ky) % 120;
        int id0 = 0, id1 = ky%120, id2 = (2*ky)%120, id3 = (3*ky)%120;
        float r0=0,r1=0,r2=0,r3=0, i0=0,i1=0,i2=0,i3=0;
        for (int m=0; m<30; ++m) {
            float2 a0 = lds[xo][4*m+0]; float2 t0 = Tm[id0];
            float2 a1 = lds[xo][4*m+1]; float2 t1 = Tm[id1];
            float2 a2 = lds[xo][4*m+2]; float2 t2 = Tm[id2];
            float2 a3 = lds[xo][4*m+3]; float2 t3 = Tm[id3];
            r0 = fmaf(a0.x,t0.x,fmaf(-a0.y,t0.y,r0)); i0 = fmaf(a0.x,t0.y,fmaf(a0.y,t0.x,i0));
            r1 = fmaf(a1.x,t1.x,fmaf(-a1.y,t1.y,r1)); i1 = fmaf(a1.x,t1.y,fmaf(a1.y,t1.x,i1));
            r2 = fmaf(a2.x,t2.x,fmaf(-a2.y,t2.y,r2)); i2 = fmaf(a2.x,t2.y,fmaf(a2.y,t2.x,i2));
            r3 = fmaf(a3.x,t3.x,fmaf(-a3.y,t3.y,r3)); i3 = fmaf(a3.x,t3.y,fmaf(a3.y,t3.x,i3));
            id0 += k4; id0 -= (id0>=120)?120:0;
            id1 += k4; id1 -= (id1>=120)?120:0;
            id2 += k4; id2 -= (id2>=120)?120:0;
            id3 += k4; id3 -= (id3>=120)?120:0;
        }
        C2[(kz*120 + ky)*120 + x0 + xo] =
            make_float2((r0+r1)+(r2+r3), (i0+i1)+(i2+i3));
    }
}

// stage 3: cfft along x + G-weighted energy + fused finalize (last block).
__global__ void __launch_bounds__(256)
fft_x_energy_kernel(const float2* __restrict__ C2,
                    const float* __restrict__ box,
                    double* __restrict__ acc,
                    unsigned* __restrict__ done,
                    float* __restrict__ out) {
    int kyc = blockIdx.x / NKZ;
    int kz  = blockIdx.x - kyc*NKZ;
    int ky0 = kyc * XCH;
    __shared__ float2 lds[XCH][121];
    __shared__ float2 Tm[120];
    for (int i = threadIdx.x; i < 120; i += 256) {
        double sd, cd; sincos(-2.0*M_PI*(double)i/120.0, &sd, &cd);
        Tm[i] = make_float2((float)cd, (float)sd);
    }
    const float2* src = C2 + (kz*120 + ky0)*120;
    for (int i = threadIdx.x; i < XCH*120; i += 256) {
        int kyo = i / 120, x = i - kyo*120;
        lds[kyo][x] = src[i];
    }
    __syncthreads();
    float ib[9]; inv3(box, ib);
    const float TWOPI = 6.283185307179586f;
    float wzf = (kz==0 || kz==60) ? 1.0f : 2.0f;
    float contrib = 0.f;
    for (int o = threadIdx.x; o < XCH*120; o += 256) {
        int kyo = o / 120, kx = o - kyo*120;
        int ky = ky0 + kyo;
        int k4  = (4*kx) % 120;
        int id0 = 0, id1 = kx%120, id2 = (2*kx)%120, id3 = (3*kx)%120;
        float r0=0,r1=0,r2=0,r3=0, i0=0,i1=0,i2=0,i3=0;
        for (int m=0; m<30; ++m) {
            float2 a0 = lds[kyo][4*m+0]; float2 t0 = Tm[id0];
            float2 a1 = lds[kyo][4*m+1]; float2 t1 = Tm[id1];
            float2 a2 = lds[kyo][4*m+2]; float2 t2 = Tm[id2];
            float2 a3 = lds[kyo][4*m+3]; float2 t3 = Tm[id3];
            r0 = fmaf(a0.x,t0.x,fmaf(-a0.y,t0.y,r0)); i0 = fmaf(a0.x,t0.y,fmaf(a0.y,t0.x,i0));
            r1 = fmaf(a1.x,t1.x,fmaf(-a1.y,t1.y,r1)); i1 = fmaf(a1.x,t1.y,fmaf(a1.y,t1.x,i1));
            r2 = fmaf(a2.x,t2.x,fmaf(-a2.y,t2.y,r2)); i2 = fmaf(a2.x,t2.y,fmaf(a2.y,t2.x,i2));
            r3 = fmaf(a3.x,t3.x,fmaf(-a3.y,t3.y,r3)); i3 = fmaf(a3.x,t3.y,fmaf(a3.y,t3.x,i3));
            id0 += k4; id0 -= (id0>=120)?120:0;
            id1 += k4; id1 -= (id1>=120)?120:0;
            id2 += k4; id2 -= (id2>=120)?120:0;
            id3 += k4; id3 -= (id3>=120)?120:0;
        }
        float re = (r0+r1)+(r2+r3);
        float im = (i0+i1)+(i2+i3);
        if (!(kx==0 && ky==0 && kz==0)) {
            float mx = (kx < 60) ? (float)kx : (float)(kx - 120);
            float my = (ky < 60) ? (float)ky : (float)(ky - 120);
            float mz = (float)kz;
            float k0 = TWOPI*(mx*ib[0] + my*ib[1] + mz*ib[2]);
            float k1 = TWOPI*(mx*ib[3] + my*ib[4] + mz*ib[5]);
            float k2 = TWOPI*(mx*ib[6] + my*ib[7] + mz*ib[8]);
            float ksq = k0*k0 + k1*k1 + k2*k2;
            float G = 12.566370614359172f * __expf(-0.5f*(float)(ALPHA_C*ALPHA_C)*ksq) / ksq;
            contrib += wzf * G * (re*re + im*im);
        }
    }
    #pragma unroll
    for (int o=32;o>0;o>>=1) contrib += __shfl_down(contrib,o,64);
    __shared__ float sm[4];
    int lane = threadIdx.x & 63, w = threadIdx.x >> 6;
    if (lane==0) sm[w] = contrib;
    __syncthreads();
    if (threadIdx.x==0) {
        atomicAdd(&acc[0], (double)(sm[0]+sm[1]+sm[2]+sm[3]));
        __threadfence();
        unsigned prev = atomicAdd(done, 1u);
        if (prev == (unsigned)(gridDim.x - 1)) {
            // last block: all energy adds are ordered before their counter bumps
            double ek  = atomicAdd(&acc[0], 0.0);   // atomic reads: coherence-point fresh
            double sq  = atomicAdd(&acc[1], 0.0);
            double sq2 = atomicAdd(&acc[2], 0.0);
            double a00=box[0],a01=box[1],a02=box[2],a10=box[3],a11=box[4],a12=box[5],a20=box[6],a21=box[7],a22=box[8];
            double det = a00*(a11*a22-a12*a21) - a01*(a10*a22-a12*a20) + a02*(a10*a21-a11*a20);
            double vol = fabs(det);
            double E = ek/(2.0*vol)
                     - 0.5*sqrt(2.0/M_PI)/ALPHA_C * sq2
                     - M_PI*ALPHA_C*ALPHA_C * sq*sq / vol;
            out[0] = (float)E;
        }
    }
}

extern "C" void kernel_launch(void* const* d_in, const int* in_sizes, int n_in,
                              void* d_out, int out_size, void* d_ws, size_t ws_size,
                              hipStream_t stream) {
    const float* coords  = (const float*)d_in[0];
    const float* box     = (const float*)d_in[1];
    const float* charges = (const float*)d_in[2];
    int n = in_sizes[0] / 3;

    char* ws = (char*)d_ws;
    double* acc     = (double*)(ws + ACC_OFF);
    unsigned* done  = (unsigned*)(ws + DONE_OFF);
    float*  buf     = (float*) (ws + BUF_OFF);
    float2* C1      = (float2*)(ws + C1_OFF);
    float2* C2      = (float2*)(ws + C2_OFF);
    int* counts     = (int*)(ws + COUNTS_OFF);
    float4* sorted  = (float4*)(ws + SORTED_OFF);

    int gA = (n + 255)/256;
    init_kernel<<<1, 1024, 0, stream>>>(counts, acc, done);
    scatter_q_kernel<<<gA, 256, 0, stream>>>(coords, box, charges, counts, sorted, acc, n);
    spread_tile_kernel<<<NTILE, 128, 0, stream>>>(sorted, counts, buf);
    fft_z_kernel<<<120*10, 256, 0, stream>>>(buf, C1);
    fft_y_kernel<<<30*NKZ, 256, 0, stream>>>(C1, C2);
    fft_x_energy_kernel<<<NKZ*30, 256, 0, stream>>>(C2, box, acc, done, (float*)d_out);
}

// Round 10
// 239.760 us; speedup vs baseline: 1.0078x; 1.0078x over previous
//
#include <hip/hip_runtime.h>
#include <math.h>

#define NMESH 120
#define NKZ 61            // rfft half-spectrum along z
#define NTOT (120*120*120)
#define ALPHA_C 1.0

#define TILE 12           // mesh cells per tile per dim
#define NTPD 10           // tiles per dim
#define NTILE 1000
#define FP 17             // footprint per dim: TILE + 5
#define FPCELLS (FP*FP*FP)   // 4913
#define FPSTRIDE 4928        // padded tile stride
#define CAP 256              // bucket capacity (Poisson(100): overflow ~1e-40)

#define YCH 12            // y-lines per fft_z block (1200 blocks)
#define XCH 4             // x per fft_y block / ky per fft_x block

// ---- workspace layout (bytes) ----
// [0,24)      : 3 doubles: ek, sum(q), sum(q^2)
// [24,28)     : u32 done-counter for fused finalize      (all zeroed by init)
// [115264, +19712000)  : float buf[1000][4928] tile footprints
// [19827264, +7027200) : float2 C1[x][kz][y]
//    counts + CAP-padded sorted atoms ALIAS the C1 region (dead before fft_z writes C1)
// C2[kz][ky][x] ALIASES buf (buf dead after fft_z)
#define ACC_OFF     0
#define DONE_OFF    24
#define BUF_OFF     115264
#define C1_OFF      19827264
#define C2_OFF      115264
#define COUNTS_OFF  C1_OFF
#define SORTED_OFF  (C1_OFF + 4096)      // 1000*256*16 = 4.096 MB < 7 MB region

__device__ inline void inv3(const float* b, float* ib) {
    float a00=b[0],a01=b[1],a02=b[2],a10=b[3],a11=b[4],a12=b[5],a20=b[6],a21=b[7],a22=b[8];
    float c00 =  a11*a22 - a12*a21;
    float c01 = -(a10*a22 - a12*a20);
    float c02 =  a10*a21 - a11*a20;
    float c10 = -(a01*a22 - a02*a21);
    float c11 =  a00*a22 - a02*a20;
    float c12 = -(a00*a21 - a01*a20);
    float c20 =  a01*a12 - a02*a11;
    float c21 = -(a00*a12 - a02*a10);
    float c22 =  a00*a11 - a01*a10;
    float det = a00*c00 + a01*c01 + a02*c02;
    float inv = 1.0f/det;
    ib[0]=c00*inv; ib[1]=c10*inv; ib[2]=c20*inv;
    ib[3]=c01*inv; ib[4]=c11*inv; ib[5]=c21*inv;
    ib[6]=c02*inv; ib[7]=c12*inv; ib[8]=c22*inv;
}

__device__ inline void atom_pos(const float* __restrict__ box, float c0, float c1, float c2,
                                float* p) {
    float ib[9]; inv3(box, ib);
    #pragma unroll
    for (int d=0; d<3; ++d)
        p[d] = (c0*ib[0+d] + c1*ib[3+d] + c2*ib[6+d]) * 120.0f;
}

__device__ inline int wrap120(int i) { return ((i % 120) + 120) % 120; }

// order-6 Lagrange weights; x = pos - (floor(pos)+0.5)
__device__ inline void lag6(float x, float* w) {
    float df[6];
    #pragma unroll
    for (int k=0;k<6;++k) df[k] = x - ((float)k - 2.5f);
    w[0] = df[1]*df[2]*df[3]*df[4]*df[5] * (-1.0f/120.0f);
    w[1] = df[0]*df[2]*df[3]*df[4]*df[5] * ( 1.0f/24.0f);
    w[2] = df[0]*df[1]*df[3]*df[4]*df[5] * (-1.0f/12.0f);
    w[3] = df[0]*df[1]*df[2]*df[4]*df[5] * ( 1.0f/12.0f);
    w[4] = df[0]*df[1]*df[2]*df[3]*df[5] * (-1.0f/24.0f);
    w[5] = df[0]*df[1]*df[2]*df[3]*df[4] * ( 1.0f/120.0f);
}

// per-dim halo decomposition: cell c -> up to 2 (tile, local) pairs
__device__ inline int halo_pairs(int c, int* t, int* l) {
    int r = c % 12, ti = c / 12, n = 0;
    t[n] = ti;          l[n] = r + 2;  n++;
    if (r < 3)  { t[n] = (ti+9)%10; l[n] = r + 14; n++; }
    if (r >= 10){ t[n] = (ti+1)%10; l[n] = r - 10; n++; }
    return n;
}

// 4-strand twiddle init for frequency k: u_j = W^j, s = W^4, W = e^{-2pi i k/120}
// Register-only twiddles: NO LDS table (R9's table caused 4.4M bank conflicts)
struct Strand4 { float ur[4], ui[4], sr, si; };
__device__ inline Strand4 strand_init(int k) {
    Strand4 st;
    double th = -2.0*M_PI*(double)k/120.0;
    double sd, cd; sincos(th, &sd, &cd);
    float w1r = (float)cd, w1i = (float)sd;
    st.ur[0]=1.f;  st.ui[0]=0.f;
    st.ur[1]=w1r;  st.ui[1]=w1i;
    st.ur[2]=w1r*w1r - w1i*w1i;        st.ui[2]=2.f*w1r*w1i;
    st.ur[3]=st.ur[2]*w1r - st.ui[2]*w1i;  st.ui[3]=st.ur[2]*w1i + st.ui[2]*w1r;
    st.sr = st.ur[2]*st.ur[2] - st.ui[2]*st.ui[2];
    st.si = 2.f*st.ur[2]*st.ui[2];
    return st;
}

__global__ void init_kernel(int* __restrict__ counts, double* __restrict__ acc,
                            unsigned* __restrict__ done) {
    int idx = threadIdx.x;
    if (idx < 3) acc[idx] = 0.0;
    if (idx == 3) *done = 0u;
    for (int i = idx; i < NTILE; i += 1024) counts[i] = 0;
}

// one-pass bucket scatter + sum(q) + sum(q^2)
__global__ void scatter_q_kernel(const float* __restrict__ coords,
                                 const float* __restrict__ box,
                                 const float* __restrict__ charges,
                                 int* __restrict__ counts,
                                 float4* __restrict__ sorted,
                                 double* __restrict__ acc, int n) {
    int i = blockIdx.x*blockDim.x + threadIdx.x;
    float v = 0.f, v2 = 0.f;
    if (i < n) {
        float p[3]; atom_pos(box, coords[3*i], coords[3*i+1], coords[3*i+2], p);
        float q = charges[i];
        v = q; v2 = q*q;
        int t[3];
        #pragma unroll
        for (int d=0; d<3; ++d) t[d] = wrap120((int)floorf(p[d])) / TILE;
        int tile = (t[0]*NTPD + t[1])*NTPD + t[2];
        int idx = atomicAdd(&counts[tile], 1);
        if (idx < CAP) sorted[tile*CAP + idx] = make_float4(p[0], p[1], p[2], q);
    }
    #pragma unroll
    for (int o=32;o>0;o>>=1) { v += __shfl_down(v,o,64); v2 += __shfl_down(v2,o,64); }
    __shared__ float s1[4], s2[4];
    int lane = threadIdx.x & 63, w = threadIdx.x >> 6;
    if (lane==0) { s1[w]=v; s2[w]=v2; }
    __syncthreads();
    if (threadIdx.x==0) {
        for (int j=1;j<4;j++) { v += s1[j]; v2 += s2[j]; }
        atomicAdd(&acc[1], (double)v);
        atomicAdd(&acc[2], (double)v2);
    }
}

// TWO WAVES per tile; each wave accumulates its atoms into a private LDS copy
// with plain RMW on exclusively-owned (a,b) slices; merge at flush.
__global__ void __launch_bounds__(128)
spread_tile_kernel(const float4* __restrict__ sorted,
                   const int* __restrict__ counts,
                   float* __restrict__ buf) {
    int tile = blockIdx.x;
    int tx = tile / (NTPD*NTPD);
    int rem = tile - tx*NTPD*NTPD;
    int ty = rem / NTPD;
    int tz = rem - ty*NTPD;
    int bx = tx*TILE, by = ty*TILE, bz = tz*TILE;

    __shared__ float accS[2][FPCELLS];   // 39.3 KB
    __shared__ float W[128][18];         // 9.2 KB
    __shared__ int   baseS[128];

    int tid  = threadIdx.x;
    int wid  = tid >> 6;
    int lane = tid & 63;
    for (int i = tid; i < FPCELLS; i += 128) { accS[0][i] = 0.f; accS[1][i] = 0.f; }

    int a = lane / 6, b = lane - a*6;            // active for lane<36
    int laneoff = a*(FP*FP) + b*FP;

    int cntT = min(counts[tile], CAP);
    const float4* src = sorted + tile*CAP;

    for (int start = 0; start < cntT; start += 128) {
        int my = start + tid;
        if (my < cntT) {
            float4 s = src[my];
            float fx = floorf(s.x);
            float wx[6]; lag6(s.x - (fx + 0.5f), wx);
            float fy = floorf(s.y);
            float wy[6]; lag6(s.y - (fy + 0.5f), wy);
            float fz = floorf(s.z);
            float wz[6]; lag6(s.z - (fz + 0.5f), wz);
            int lx = wrap120((int)fx) - bx;
            int ly = wrap120((int)fy) - by;
            int lz = wrap120((int)fz) - bz;
            baseS[tid] = (lx*FP + ly)*FP + lz;
            #pragma unroll
            for (int k=0;k<6;++k) {
                W[tid][k]    = wx[k]*s.w;
                W[tid][6+k]  = wy[k];
                W[tid][12+k] = wz[k];
            }
        }
        __syncthreads();
        int jn = cntT - start - wid*64;
        jn = (jn > 64) ? 64 : jn;
        if (lane < 36) {
            for (int j = 0; j < jn; ++j) {
                int row = wid*64 + j;
                float w2 = W[row][a] * W[row][6+b];
                int ad = baseS[row] + laneoff;
                #pragma unroll
                for (int c=0;c<6;++c)
                    accS[wid][ad + c] += w2 * W[row][12+c];
            }
        }
        __syncthreads();
    }

    for (int i = tid; i < FPCELLS; i += 128)
        buf[(size_t)tile * FPSTRIDE + i] = accS[0][i] + accS[1][i];
}

// stage 1: halo-gather + rfft along z, 4-strand register recurrence. out C1[x][kz][y].
__global__ void __launch_bounds__(256)
fft_z_kernel(const float* __restrict__ buf,
             float2* __restrict__ C1) {
    int x  = blockIdx.x / 10;
    int y0 = (blockIdx.x - x*10) * YCH;
    __shared__ float lds[YCH][121];

    int txA[2], lxA[2];
    int nx = halo_pairs(x, txA, lxA);

    for (int i = threadIdx.x; i < YCH*120; i += 256) {
        int yl = i / 120, z = i - yl*120;
        int tyA[2], lyA[2]; int ny = halo_pairs(y0 + yl, tyA, lyA);
        int tzA[2], lzA[2]; int nz = halo_pairs(z, tzA, lzA);
        float s = 0.f;
        for (int ii=0; ii<nx; ++ii)
            for (int jj=0; jj<ny; ++jj)
                for (int kk=0; kk<nz; ++kk) {
                    int tile = (txA[ii]*NTPD + tyA[jj])*NTPD + tzA[kk];
                    int cell = (lxA[ii]*FP + lyA[jj])*FP + lzA[kk];
                    s += buf[(size_t)tile*FPSTRIDE + cell];
                }
        lds[yl][z] = s;
    }
    __syncthreads();
    for (int o = threadIdx.x; o < YCH*NKZ; o += 256) {
        int kz = o / YCH, yl = o - kz*YCH;
        Strand4 st = strand_init(kz);
        float rr[4] = {0.f,0.f,0.f,0.f}, ii2[4] = {0.f,0.f,0.f,0.f};
        for (int m=0; m<30; ++m) {
            #pragma unroll
            for (int j=0;j<4;++j) {
                float v = lds[yl][4*m+j];
                rr[j]  = fmaf(v, st.ur[j], rr[j]);
                ii2[j] = fmaf(v, st.ui[j], ii2[j]);
                float nr = st.ur[j]*st.sr - st.ui[j]*st.si;
                float ni = st.ur[j]*st.si + st.ui[j]*st.sr;
                st.ur[j] = nr; st.ui[j] = ni;
            }
        }
        float re = (rr[0]+rr[1]) + (rr[2]+rr[3]);
        float im = (ii2[0]+ii2[1]) + (ii2[2]+ii2[3]);
        C1[(x*NKZ + kz)*120 + y0 + yl] = make_float2(re, im);
    }
}

// stage 2: cfft along y, 4-strand. block = (4 consecutive x, kz). out C2[kz][ky][x].
__global__ void __launch_bounds__(256)
fft_y_kernel(const float2* __restrict__ C1,
             float2* __restrict__ C2) {
    int xc = blockIdx.x / NKZ;
    int kz = blockIdx.x - xc*NKZ;
    int x0 = xc * XCH;
    __shared__ float2 lds[XCH][121];
    for (int i = threadIdx.x; i < XCH*120; i += 256) {
        int xo = i / 120, y = i - xo*120;
        lds[xo][y] = C1[((x0+xo)*NKZ + kz)*120 + y];
    }
    __syncthreads();
    for (int o = threadIdx.x; o < XCH*120; o += 256) {
        int ky = o >> 2, xo = o & 3;
        Strand4 st = strand_init(ky);
        float rr[4] = {0.f,0.f,0.f,0.f}, ii2[4] = {0.f,0.f,0.f,0.f};
        for (int m=0; m<30; ++m) {
            #pragma unroll
            for (int j=0;j<4;++j) {
                float2 aa = lds[xo][4*m+j];
                rr[j]  = fmaf(aa.x, st.ur[j], fmaf(-aa.y, st.ui[j], rr[j]));
                ii2[j] = fmaf(aa.x, st.ui[j], fmaf( aa.y, st.ur[j], ii2[j]));
                float nr = st.ur[j]*st.sr - st.ui[j]*st.si;
                float ni = st.ur[j]*st.si + st.ui[j]*st.sr;
                st.ur[j] = nr; st.ui[j] = ni;
            }
        }
        float re = (rr[0]+rr[1]) + (rr[2]+rr[3]);
        float im = (ii2[0]+ii2[1]) + (ii2[2]+ii2[3]);
        C2[(kz*120 + ky)*120 + x0 + xo] = make_float2(re, im);
    }
}

// stage 3: cfft along x (4-strand) + G-weighted energy + fused finalize (last block).
__global__ void __launch_bounds__(256)
fft_x_energy_kernel(const float2* __restrict__ C2,
                    const float* __restrict__ box,
                    double* __restrict__ acc,
                    unsigned* __restrict__ done,
                    float* __restrict__ out) {
    int kyc = blockIdx.x / NKZ;
    int kz  = blockIdx.x - kyc*NKZ;
    int ky0 = kyc * XCH;
    __shared__ float2 lds[XCH][121];
    const float2* src = C2 + (kz*120 + ky0)*120;
    for (int i = threadIdx.x; i < XCH*120; i += 256) {
        int kyo = i / 120, x = i - kyo*120;
        lds[kyo][x] = src[i];
    }
    __syncthreads();
    float ib[9]; inv3(box, ib);
    const float TWOPI = 6.283185307179586f;
    float wzf = (kz==0 || kz==60) ? 1.0f : 2.0f;
    float contrib = 0.f;
    for (int o = threadIdx.x; o < XCH*120; o += 256) {
        int kyo = o / 120, kx = o - kyo*120;
        int ky = ky0 + kyo;
        Strand4 st = strand_init(kx);
        float rr[4] = {0.f,0.f,0.f,0.f}, ii2[4] = {0.f,0.f,0.f,0.f};
        for (int m=0; m<30; ++m) {
            #pragma unroll
            for (int j=0;j<4;++j) {
                float2 aa = lds[kyo][4*m+j];
                rr[j]  = fmaf(aa.x, st.ur[j], fmaf(-aa.y, st.ui[j], rr[j]));
                ii2[j] = fmaf(aa.x, st.ui[j], fmaf( aa.y, st.ur[j], ii2[j]));
                float nr = st.ur[j]*st.sr - st.ui[j]*st.si;
                float ni = st.ur[j]*st.si + st.ui[j]*st.sr;
                st.ur[j] = nr; st.ui[j] = ni;
            }
        }
        float re = (rr[0]+rr[1]) + (rr[2]+rr[3]);
        float im = (ii2[0]+ii2[1]) + (ii2[2]+ii2[3]);
        if (!(kx==0 && ky==0 && kz==0)) {
            float mx = (kx < 60) ? (float)kx : (float)(kx - 120);
            float my = (ky < 60) ? (float)ky : (float)(ky - 120);
            float mz = (float)kz;
            float k0 = TWOPI*(mx*ib[0] + my*ib[1] + mz*ib[2]);
            float k1 = TWOPI*(mx*ib[3] + my*ib[4] + mz*ib[5]);
            float k2 = TWOPI*(mx*ib[6] + my*ib[7] + mz*ib[8]);
            float ksq = k0*k0 + k1*k1 + k2*k2;
            float G = 12.566370614359172f * __expf(-0.5f*(float)(ALPHA_C*ALPHA_C)*ksq) / ksq;
            contrib += wzf * G * (re*re + im*im);
        }
    }
    #pragma unroll
    for (int o=32;o>0;o>>=1) contrib += __shfl_down(contrib,o,64);
    __shared__ float sm[4];
    int lane = threadIdx.x & 63, w = threadIdx.x >> 6;
    if (lane==0) sm[w] = contrib;
    __syncthreads();
    if (threadIdx.x==0) {
        atomicAdd(&acc[0], (double)(sm[0]+sm[1]+sm[2]+sm[3]));
        __threadfence();
        unsigned prev = atomicAdd(done, 1u);
        if (prev == (unsigned)(gridDim.x - 1)) {
            // last block: all energy adds are ordered before their counter bumps
            double ek  = atomicAdd(&acc[0], 0.0);   // atomic reads: coherence-point fresh
            double sq  = atomicAdd(&acc[1], 0.0);
            double sq2 = atomicAdd(&acc[2], 0.0);
            double a00=box[0],a01=box[1],a02=box[2],a10=box[3],a11=box[4],a12=box[5],a20=box[6],a21=box[7],a22=box[8];
            double det = a00*(a11*a22-a12*a21) - a01*(a10*a22-a12*a20) + a02*(a10*a21-a11*a20);
            double vol = fabs(det);
            double E = ek/(2.0*vol)
                     - 0.5*sqrt(2.0/M_PI)/ALPHA_C * sq2
                     - M_PI*ALPHA_C*ALPHA_C * sq*sq / vol;
            out[0] = (float)E;
        }
    }
}

extern "C" void kernel_launch(void* const* d_in, const int* in_sizes, int n_in,
                              void* d_out, int out_size, void* d_ws, size_t ws_size,
                              hipStream_t stream) {
    const float* coords  = (const float*)d_in[0];
    const float* box     = (const float*)d_in[1];
    const float* charges = (const float*)d_in[2];
    int n = in_sizes[0] / 3;

    char* ws = (char*)d_ws;
    double* acc     = (double*)(ws + ACC_OFF);
    unsigned* done  = (unsigned*)(ws + DONE_OFF);
    float*  buf     = (float*) (ws + BUF_OFF);
    float2* C1      = (float2*)(ws + C1_OFF);
    float2* C2      = (float2*)(ws + C2_OFF);
    int* counts     = (int*)(ws + COUNTS_OFF);
    float4* sorted  = (float4*)(ws + SORTED_OFF);

    int gA = (n + 255)/256;
    init_kernel<<<1, 1024, 0, stream>>>(counts, acc, done);
    scatter_q_kernel<<<gA, 256, 0, stream>>>(coords, box, charges, counts, sorted, acc, n);
    spread_tile_kernel<<<NTILE, 128, 0, stream>>>(sorted, counts, buf);
    fft_z_kernel<<<120*10, 256, 0, stream>>>(buf, C1);
    fft_y_kernel<<<30*NKZ, 256, 0, stream>>>(C1, C2);
    fft_x_energy_kernel<<<NKZ*30, 256, 0, stream>>>(C2, box, acc, done, (float*)d_out);
}

// Round 11
// 210.651 us; speedup vs baseline: 1.1471x; 1.1382x over previous
//
#include <hip/hip_runtime.h>
#include <math.h>

#define NMESH 120
#define NKZ 61            // rfft half-spectrum along z
#define NTOT (120*120*120)
#define ALPHA_C 1.0

#define TILE 12           // mesh cells per tile per dim
#define NTPD 10           // tiles per dim
#define NTILE 1000
#define FP 17             // footprint per dim: TILE + 5
#define FPCELLS (FP*FP*FP)   // 4913
#define FPSTRIDE 4928        // padded tile stride
#define CAP 256              // bucket capacity (Poisson(100): overflow ~1e-40)

#define YCH 12            // y-lines per fft_z block (1200 blocks)
#define XCH 4             // x per fft_y block / ky per fft_x block

// ---- workspace layout (bytes) ----
// [0,24)      : 3 doubles: ek, sum(q), sum(q^2)
// [24,28)     : u32 done-counter for fused finalize      (all zeroed by init)
// [115264, +19712000)  : float buf[1000][4928] tile footprints
// [19827264, +7027200) : float2 C1[x][kz][y]
//    counts + CAP-padded sorted atoms ALIAS the C1 region (dead before fft_z writes C1)
// C2[kz][ky][x] ALIASES buf (buf dead after fft_z)
#define ACC_OFF     0
#define DONE_OFF    24
#define BUF_OFF     115264
#define C1_OFF      19827264
#define C2_OFF      115264
#define COUNTS_OFF  C1_OFF
#define SORTED_OFF  (C1_OFF + 4096)      // 1000*256*16 = 4.096 MB < 7 MB region

__device__ inline void inv3(const float* b, float* ib) {
    float a00=b[0],a01=b[1],a02=b[2],a10=b[3],a11=b[4],a12=b[5],a20=b[6],a21=b[7],a22=b[8];
    float c00 =  a11*a22 - a12*a21;
    float c01 = -(a10*a22 - a12*a20);
    float c02 =  a10*a21 - a11*a20;
    float c10 = -(a01*a22 - a02*a21);
    float c11 =  a00*a22 - a02*a20;
    float c12 = -(a00*a21 - a01*a20);
    float c20 =  a01*a12 - a02*a11;
    float c21 = -(a00*a12 - a02*a10);
    float c22 =  a00*a11 - a01*a10;
    float det = a00*c00 + a01*c01 + a02*c02;
    float inv = 1.0f/det;
    ib[0]=c00*inv; ib[1]=c10*inv; ib[2]=c20*inv;
    ib[3]=c01*inv; ib[4]=c11*inv; ib[5]=c21*inv;
    ib[6]=c02*inv; ib[7]=c12*inv; ib[8]=c22*inv;
}

__device__ inline void atom_pos(const float* __restrict__ box, float c0, float c1, float c2,
                                float* p) {
    float ib[9]; inv3(box, ib);
    #pragma unroll
    for (int d=0; d<3; ++d)
        p[d] = (c0*ib[0+d] + c1*ib[3+d] + c2*ib[6+d]) * 120.0f;
}

__device__ inline int wrap120(int i) { return ((i % 120) + 120) % 120; }

// order-6 Lagrange weights; x = pos - (floor(pos)+0.5)
__device__ inline void lag6(float x, float* w) {
    float df[6];
    #pragma unroll
    for (int k=0;k<6;++k) df[k] = x - ((float)k - 2.5f);
    w[0] = df[1]*df[2]*df[3]*df[4]*df[5] * (-1.0f/120.0f);
    w[1] = df[0]*df[2]*df[3]*df[4]*df[5] * ( 1.0f/24.0f);
    w[2] = df[0]*df[1]*df[3]*df[4]*df[5] * (-1.0f/12.0f);
    w[3] = df[0]*df[1]*df[2]*df[4]*df[5] * ( 1.0f/12.0f);
    w[4] = df[0]*df[1]*df[2]*df[3]*df[5] * (-1.0f/24.0f);
    w[5] = df[0]*df[1]*df[2]*df[3]*df[4] * ( 1.0f/120.0f);
}

// per-dim halo decomposition: cell c -> up to 2 (tile, local) pairs
__device__ inline int halo_pairs(int c, int* t, int* l) {
    int r = c % 12, ti = c / 12, n = 0;
    t[n] = ti;          l[n] = r + 2;  n++;
    if (r < 3)  { t[n] = (ti+9)%10; l[n] = r + 14; n++; }
    if (r >= 10){ t[n] = (ti+1)%10; l[n] = r - 10; n++; }
    return n;
}

__global__ void init_kernel(int* __restrict__ counts, double* __restrict__ acc,
                            unsigned* __restrict__ done) {
    int idx = threadIdx.x;
    if (idx < 3) acc[idx] = 0.0;
    if (idx == 3) *done = 0u;
    for (int i = idx; i < NTILE; i += 1024) counts[i] = 0;
}

// one-pass bucket scatter + sum(q) + sum(q^2)
__global__ void scatter_q_kernel(const float* __restrict__ coords,
                                 const float* __restrict__ box,
                                 const float* __restrict__ charges,
                                 int* __restrict__ counts,
                                 float4* __restrict__ sorted,
                                 double* __restrict__ acc, int n) {
    int i = blockIdx.x*blockDim.x + threadIdx.x;
    float v = 0.f, v2 = 0.f;
    if (i < n) {
        float p[3]; atom_pos(box, coords[3*i], coords[3*i+1], coords[3*i+2], p);
        float q = charges[i];
        v = q; v2 = q*q;
        int t[3];
        #pragma unroll
        for (int d=0; d<3; ++d) t[d] = wrap120((int)floorf(p[d])) / TILE;
        int tile = (t[0]*NTPD + t[1])*NTPD + t[2];
        int idx = atomicAdd(&counts[tile], 1);
        if (idx < CAP) sorted[tile*CAP + idx] = make_float4(p[0], p[1], p[2], q);
    }
    #pragma unroll
    for (int o=32;o>0;o>>=1) { v += __shfl_down(v,o,64); v2 += __shfl_down(v2,o,64); }
    __shared__ float s1[4], s2[4];
    int lane = threadIdx.x & 63, w = threadIdx.x >> 6;
    if (lane==0) { s1[w]=v; s2[w]=v2; }
    __syncthreads();
    if (threadIdx.x==0) {
        for (int j=1;j<4;j++) { v += s1[j]; v2 += s2[j]; }
        atomicAdd(&acc[1], (double)v);
        atomicAdd(&acc[2], (double)v2);
    }
}

// TWO WAVES per tile; each wave accumulates its atoms into a private LDS copy
// with plain RMW on exclusively-owned (a,b) slices; merge at flush.
__global__ void __launch_bounds__(128)
spread_tile_kernel(const float4* __restrict__ sorted,
                   const int* __restrict__ counts,
                   float* __restrict__ buf) {
    int tile = blockIdx.x;
    int tx = tile / (NTPD*NTPD);
    int rem = tile - tx*NTPD*NTPD;
    int ty = rem / NTPD;
    int tz = rem - ty*NTPD;
    int bx = tx*TILE, by = ty*TILE, bz = tz*TILE;

    __shared__ float accS[2][FPCELLS];   // 39.3 KB
    __shared__ float W[128][18];         // 9.2 KB
    __shared__ int   baseS[128];

    int tid  = threadIdx.x;
    int wid  = tid >> 6;
    int lane = tid & 63;
    for (int i = tid; i < FPCELLS; i += 128) { accS[0][i] = 0.f; accS[1][i] = 0.f; }

    int a = lane / 6, b = lane - a*6;            // active for lane<36
    int laneoff = a*(FP*FP) + b*FP;

    int cntT = min(counts[tile], CAP);
    const float4* src = sorted + tile*CAP;

    for (int start = 0; start < cntT; start += 128) {
        int my = start + tid;
        if (my < cntT) {
            float4 s = src[my];
            float fx = floorf(s.x);
            float wx[6]; lag6(s.x - (fx + 0.5f), wx);
            float fy = floorf(s.y);
            float wy[6]; lag6(s.y - (fy + 0.5f), wy);
            float fz = floorf(s.z);
            float wz[6]; lag6(s.z - (fz + 0.5f), wz);
            int lx = wrap120((int)fx) - bx;
            int ly = wrap120((int)fy) - by;
            int lz = wrap120((int)fz) - bz;
            baseS[tid] = (lx*FP + ly)*FP + lz;
            #pragma unroll
            for (int k=0;k<6;++k) {
                W[tid][k]    = wx[k]*s.w;
                W[tid][6+k]  = wy[k];
                W[tid][12+k] = wz[k];
            }
        }
        __syncthreads();
        int jn = cntT - start - wid*64;
        jn = (jn > 64) ? 64 : jn;
        if (lane < 36) {
            for (int j = 0; j < jn; ++j) {
                int row = wid*64 + j;
                float w2 = W[row][a] * W[row][6+b];
                int ad = baseS[row] + laneoff;
                #pragma unroll
                for (int c=0;c<6;++c)
                    accS[wid][ad + c] += w2 * W[row][12+c];
            }
        }
        __syncthreads();
    }

    for (int i = tid; i < FPCELLS; i += 128)
        buf[(size_t)tile * FPSTRIDE + i] = accS[0][i] + accS[1][i];
}

// ---- radix-4 decimated 120-point DFT main loop (uniform for all stages) ----
// X[k] = sum_{j<30} Y[k&3][j] * W^{k*j};  2 strands (even/odd j) for ILP.
#define DFT30_BODY(Yp, kfreq, RE, IM)                                        \
    double sd_, cd_; sincos(-2.0*M_PI*(double)(kfreq)/120.0, &sd_, &cd_);    \
    float w1r=(float)cd_, w1i=(float)sd_;                                    \
    float w2r = w1r*w1r - w1i*w1i, w2i = 2.f*w1r*w1i;                        \
    float ar=1.f, ai=0.f, br=w1r, bi=w1i;                                    \
    float r0_=0.f,i0_=0.f,r1_=0.f,i1_=0.f;                                   \
    _Pragma("unroll")                                                        \
    for (int s_=0;s_<15;++s_) {                                              \
        float2 ya = (Yp)[2*s_], yb = (Yp)[2*s_+1];                           \
        r0_ = fmaf(ya.x, ar, fmaf(-ya.y, ai, r0_));                          \
        i0_ = fmaf(ya.x, ai, fmaf( ya.y, ar, i0_));                          \
        r1_ = fmaf(yb.x, br, fmaf(-yb.y, bi, r1_));                          \
        i1_ = fmaf(yb.x, bi, fmaf( yb.y, br, i1_));                          \
        float nar = ar*w2r - ai*w2i, nai = ar*w2i + ai*w2r; ar=nar; ai=nai;  \
        float nbr = br*w2r - bi*w2i, nbi = br*w2i + bi*w2r; br=nbr; bi=nbi;  \
    }                                                                        \
    float RE = r0_+r1_, IM = i0_+i1_;

// stage 1: halo-gather + rfft along z (radix-4 pre-combine). out C1[x][kz][y].
__global__ void __launch_bounds__(256)
fft_z_kernel(const float* __restrict__ buf,
             float2* __restrict__ C1) {
    int x  = blockIdx.x / 10;
    int y0 = (blockIdx.x - x*10) * YCH;
    __shared__ float  lin[YCH][121];
    __shared__ float2 Y[YCH][4][31];     // padded: conflict-free reads

    int txA[2], lxA[2];
    int nx = halo_pairs(x, txA, lxA);

    for (int i = threadIdx.x; i < YCH*120; i += 256) {
        int yl = i / 120, z = i - yl*120;
        int tyA[2], lyA[2]; int ny = halo_pairs(y0 + yl, tyA, lyA);
        int tzA[2], lzA[2]; int nz = halo_pairs(z, tzA, lzA);
        float s = 0.f;
        for (int ii=0; ii<nx; ++ii)
            for (int jj=0; jj<ny; ++jj)
                for (int kk=0; kk<nz; ++kk) {
                    int tile = (txA[ii]*NTPD + tyA[jj])*NTPD + tzA[kk];
                    int cell = (lxA[ii]*FP + lyA[jj])*FP + lzA[kk];
                    s += buf[(size_t)tile*FPSTRIDE + cell];
                }
        lin[yl][z] = s;
    }
    __syncthreads();
    // radix-4 combine: z = 30m + j ; W^(30mk) = (-i)^(mk), real input
    for (int t = threadIdx.x; t < YCH*30; t += 256) {
        int yl = t / 30, j = t - (t/30)*30;
        float x0 = lin[yl][j], x1 = lin[yl][j+30], x2 = lin[yl][j+60], x3 = lin[yl][j+90];
        float s02 = x0+x2, d02 = x0-x2, s13 = x1+x3, d13 = x1-x3;
        Y[yl][0][j] = make_float2(s02+s13, 0.f);
        Y[yl][2][j] = make_float2(s02-s13, 0.f);
        Y[yl][1][j] = make_float2(d02, -d13);
        Y[yl][3][j] = make_float2(d02,  d13);
    }
    __syncthreads();
    for (int o = threadIdx.x; o < YCH*NKZ; o += 256) {
        int kz = o / YCH, yl = o - (o/YCH)*YCH;
        const float2* Yp = Y[yl][kz & 3];
        DFT30_BODY(Yp, kz, re, im)
        C1[(x*NKZ + kz)*120 + y0 + yl] = make_float2(re, im);
    }
}

// stage 2: cfft along y (radix-4). block = (4 consecutive x, kz). out C2[kz][ky][x].
__global__ void __launch_bounds__(256)
fft_y_kernel(const float2* __restrict__ C1,
             float2* __restrict__ C2) {
    int xc = blockIdx.x / NKZ;
    int kz = blockIdx.x - xc*NKZ;
    int x0 = xc * XCH;
    __shared__ float2 lin[XCH][121];
    __shared__ float2 Y[XCH][4][31];
    for (int i = threadIdx.x; i < XCH*120; i += 256) {
        int xo = i / 120, y = i - (i/120)*120;
        lin[xo][y] = C1[((x0+xo)*NKZ + kz)*120 + y];
    }
    __syncthreads();
    for (int t = threadIdx.x; t < XCH*30; t += 256) {
        int xo = t / 30, j = t - (t/30)*30;
        float2 a0 = lin[xo][j], a1 = lin[xo][j+30], a2 = lin[xo][j+60], a3 = lin[xo][j+90];
        float s02r=a0.x+a2.x, s02i=a0.y+a2.y, d02r=a0.x-a2.x, d02i=a0.y-a2.y;
        float s13r=a1.x+a3.x, s13i=a1.y+a3.y, d13r=a1.x-a3.x, d13i=a1.y-a3.y;
        Y[xo][0][j] = make_float2(s02r+s13r, s02i+s13i);
        Y[xo][2][j] = make_float2(s02r-s13r, s02i-s13i);
        Y[xo][1][j] = make_float2(d02r+d13i, d02i-d13r);
        Y[xo][3][j] = make_float2(d02r-d13i, d02i+d13r);
    }
    __syncthreads();
    for (int o = threadIdx.x; o < XCH*120; o += 256) {
        int ky = o >> 2, xo = o & 3;
        const float2* Yp = Y[xo][ky & 3];
        DFT30_BODY(Yp, ky, re, im)
        C2[(kz*120 + ky)*120 + x0 + xo] = make_float2(re, im);
    }
}

// stage 3: cfft along x (radix-4) + G-weighted energy + fused finalize.
__global__ void __launch_bounds__(256)
fft_x_energy_kernel(const float2* __restrict__ C2,
                    const float* __restrict__ box,
                    double* __restrict__ acc,
                    unsigned* __restrict__ done,
                    float* __restrict__ out) {
    int kyc = blockIdx.x / NKZ;
    int kz  = blockIdx.x - kyc*NKZ;
    int ky0 = kyc * XCH;
    __shared__ float2 lin[XCH][121];
    __shared__ float2 Y[XCH][4][31];
    const float2* src = C2 + (kz*120 + ky0)*120;
    for (int i = threadIdx.x; i < XCH*120; i += 256) {
        int kyo = i / 120, xx = i - (i/120)*120;
        lin[kyo][xx] = src[i];
    }
    __syncthreads();
    for (int t = threadIdx.x; t < XCH*30; t += 256) {
        int kyo = t / 30, j = t - (t/30)*30;
        float2 a0 = lin[kyo][j], a1 = lin[kyo][j+30], a2 = lin[kyo][j+60], a3 = lin[kyo][j+90];
        float s02r=a0.x+a2.x, s02i=a0.y+a2.y, d02r=a0.x-a2.x, d02i=a0.y-a2.y;
        float s13r=a1.x+a3.x, s13i=a1.y+a3.y, d13r=a1.x-a3.x, d13i=a1.y-a3.y;
        Y[kyo][0][j] = make_float2(s02r+s13r, s02i+s13i);
        Y[kyo][2][j] = make_float2(s02r-s13r, s02i-s13i);
        Y[kyo][1][j] = make_float2(d02r+d13i, d02i-d13r);
        Y[kyo][3][j] = make_float2(d02r-d13i, d02i+d13r);
    }
    __syncthreads();
    float ib[9]; inv3(box, ib);
    const float TWOPI = 6.283185307179586f;
    float wzf = (kz==0 || kz==60) ? 1.0f : 2.0f;
    float contrib = 0.f;
    for (int o = threadIdx.x; o < XCH*120; o += 256) {
        int kyo = o / 120, kx = o - (o/120)*120;
        int ky = ky0 + kyo;
        const float2* Yp = Y[kyo][kx & 3];
        DFT30_BODY(Yp, kx, re, im)
        if (!(kx==0 && ky==0 && kz==0)) {
            float mx = (kx < 60) ? (float)kx : (float)(kx - 120);
            float my = (ky < 60) ? (float)ky : (float)(ky - 120);
            float mz = (float)kz;
            float k0 = TWOPI*(mx*ib[0] + my*ib[1] + mz*ib[2]);
            float k1 = TWOPI*(mx*ib[3] + my*ib[4] + mz*ib[5]);
            float k2 = TWOPI*(mx*ib[6] + my*ib[7] + mz*ib[8]);
            float ksq = k0*k0 + k1*k1 + k2*k2;
            float G = 12.566370614359172f * __expf(-0.5f*(float)(ALPHA_C*ALPHA_C)*ksq) / ksq;
            contrib += wzf * G * (re*re + im*im);
        }
    }
    #pragma unroll
    for (int o=32;o>0;o>>=1) contrib += __shfl_down(contrib,o,64);
    __shared__ float sm[4];
    int lane = threadIdx.x & 63, w = threadIdx.x >> 6;
    if (lane==0) sm[w] = contrib;
    __syncthreads();
    if (threadIdx.x==0) {
        atomicAdd(&acc[0], (double)(sm[0]+sm[1]+sm[2]+sm[3]));
        __threadfence();
        unsigned prev = atomicAdd(done, 1u);
        if (prev == (unsigned)(gridDim.x - 1)) {
            double ek  = atomicAdd(&acc[0], 0.0);
            double sq  = atomicAdd(&acc[1], 0.0);
            double sq2 = atomicAdd(&acc[2], 0.0);
            double a00=box[0],a01=box[1],a02=box[2],a10=box[3],a11=box[4],a12=box[5],a20=box[6],a21=box[7],a22=box[8];
            double det = a00*(a11*a22-a12*a21) - a01*(a10*a22-a12*a20) + a02*(a10*a21-a11*a20);
            double vol = fabs(det);
            double E = ek/(2.0*vol)
                     - 0.5*sqrt(2.0/M_PI)/ALPHA_C * sq2
                     - M_PI*ALPHA_C*ALPHA_C * sq*sq / vol;
            out[0] = (float)E;
        }
    }
}

extern "C" void kernel_launch(void* const* d_in, const int* in_sizes, int n_in,
                              void* d_out, int out_size, void* d_ws, size_t ws_size,
                              hipStream_t stream) {
    const float* coords  = (const float*)d_in[0];
    const float* box     = (const float*)d_in[1];
    const float* charges = (const float*)d_in[2];
    int n = in_sizes[0] / 3;

    char* ws = (char*)d_ws;
    double* acc     = (double*)(ws + ACC_OFF);
    unsigned* done  = (unsigned*)(ws + DONE_OFF);
    float*  buf     = (float*) (ws + BUF_OFF);
    float2* C1      = (float2*)(ws + C1_OFF);
    float2* C2      = (float2*)(ws + C2_OFF);
    int* counts     = (int*)(ws + COUNTS_OFF);
    float4* sorted  = (float4*)(ws + SORTED_OFF);

    int gA = (n + 255)/256;
    init_kernel<<<1, 1024, 0, stream>>>(counts, acc, done);
    scatter_q_kernel<<<gA, 256, 0, stream>>>(coords, box, charges, counts, sorted, acc, n);
    spread_tile_kernel<<<NTILE, 128, 0, stream>>>(sorted, counts, buf);
    fft_z_kernel<<<120*10, 256, 0, stream>>>(buf, C1);
    fft_y_kernel<<<30*NKZ, 256, 0, stream>>>(C1, C2);
    fft_x_energy_kernel<<<NKZ*30, 256, 0, stream>>>(C2, box, acc, done, (float*)d_out);
}

// Round 12
// 184.055 us; speedup vs baseline: 1.3128x; 1.1445x over previous
//
#include <hip/hip_runtime.h>
#include <math.h>

#define NMESH 120
#define NKZ 61            // rfft half-spectrum along z
#define NTOT (120*120*120)
#define ALPHA_C 1.0

#define TILE 12           // mesh cells per tile per dim
#define NTPD 10           // tiles per dim
#define NTILE 1000
#define FP 17             // footprint per dim: TILE + 5
#define FPCELLS (FP*FP*FP)   // 4913
#define FPSTRIDE 4928        // padded tile stride
#define CAP 256              // bucket capacity (Poisson(100): overflow ~1e-40)

#define YCH 12            // y-lines per fft_z block (1200 blocks)
#define XCH 4             // x per fft_y block / ky per fft_x block

// ---- workspace layout (bytes) ----
// [0,24)      : 3 doubles: ek, sum(q), sum(q^2)     (zeroed by init)
// [115264, +19712000)  : float buf[1000][4928] tile footprints
// [19827264, +7027200) : float2 C1[x][kz][y]
//    counts + CAP-padded sorted atoms ALIAS the C1 region (dead before fft_z writes C1)
// C2[kz][ky][x] ALIASES buf (buf dead after fft_z)
#define ACC_OFF     0
#define BUF_OFF     115264
#define C1_OFF      19827264
#define C2_OFF      115264
#define COUNTS_OFF  C1_OFF
#define SORTED_OFF  (C1_OFF + 4096)      // 1000*256*16 = 4.096 MB < 7 MB region

__device__ inline void inv3(const float* b, float* ib) {
    float a00=b[0],a01=b[1],a02=b[2],a10=b[3],a11=b[4],a12=b[5],a20=b[6],a21=b[7],a22=b[8];
    float c00 =  a11*a22 - a12*a21;
    float c01 = -(a10*a22 - a12*a20);
    float c02 =  a10*a21 - a11*a20;
    float c10 = -(a01*a22 - a02*a21);
    float c11 =  a00*a22 - a02*a20;
    float c12 = -(a00*a21 - a01*a20);
    float c20 =  a01*a12 - a02*a11;
    float c21 = -(a00*a12 - a02*a10);
    float c22 =  a00*a11 - a01*a10;
    float det = a00*c00 + a01*c01 + a02*c02;
    float inv = 1.0f/det;
    ib[0]=c00*inv; ib[1]=c10*inv; ib[2]=c20*inv;
    ib[3]=c01*inv; ib[4]=c11*inv; ib[5]=c21*inv;
    ib[6]=c02*inv; ib[7]=c12*inv; ib[8]=c22*inv;
}

__device__ inline void atom_pos(const float* __restrict__ box, float c0, float c1, float c2,
                                float* p) {
    float ib[9]; inv3(box, ib);
    #pragma unroll
    for (int d=0; d<3; ++d)
        p[d] = (c0*ib[0+d] + c1*ib[3+d] + c2*ib[6+d]) * 120.0f;
}

__device__ inline int wrap120(int i) { return ((i % 120) + 120) % 120; }

// order-6 Lagrange weights; x = pos - (floor(pos)+0.5)
__device__ inline void lag6(float x, float* w) {
    float df[6];
    #pragma unroll
    for (int k=0;k<6;++k) df[k] = x - ((float)k - 2.5f);
    w[0] = df[1]*df[2]*df[3]*df[4]*df[5] * (-1.0f/120.0f);
    w[1] = df[0]*df[2]*df[3]*df[4]*df[5] * ( 1.0f/24.0f);
    w[2] = df[0]*df[1]*df[3]*df[4]*df[5] * (-1.0f/12.0f);
    w[3] = df[0]*df[1]*df[2]*df[4]*df[5] * ( 1.0f/12.0f);
    w[4] = df[0]*df[1]*df[2]*df[3]*df[5] * (-1.0f/24.0f);
    w[5] = df[0]*df[1]*df[2]*df[3]*df[4] * ( 1.0f/120.0f);
}

// per-dim halo decomposition: cell c -> up to 2 (tile, local) pairs
__device__ inline int halo_pairs(int c, int* t, int* l) {
    int r = c % 12, ti = c / 12, n = 0;
    t[n] = ti;          l[n] = r + 2;  n++;
    if (r < 3)  { t[n] = (ti+9)%10; l[n] = r + 14; n++; }
    if (r >= 10){ t[n] = (ti+1)%10; l[n] = r - 10; n++; }
    return n;
}

__global__ void init_kernel(int* __restrict__ counts, double* __restrict__ acc) {
    int idx = threadIdx.x;
    if (idx < 3) acc[idx] = 0.0;
    for (int i = idx; i < NTILE; i += 1024) counts[i] = 0;
}

// one-pass bucket scatter + sum(q) + sum(q^2)
__global__ void scatter_q_kernel(const float* __restrict__ coords,
                                 const float* __restrict__ box,
                                 const float* __restrict__ charges,
                                 int* __restrict__ counts,
                                 float4* __restrict__ sorted,
                                 double* __restrict__ acc, int n) {
    int i = blockIdx.x*blockDim.x + threadIdx.x;
    float v = 0.f, v2 = 0.f;
    if (i < n) {
        float p[3]; atom_pos(box, coords[3*i], coords[3*i+1], coords[3*i+2], p);
        float q = charges[i];
        v = q; v2 = q*q;
        int t[3];
        #pragma unroll
        for (int d=0; d<3; ++d) t[d] = wrap120((int)floorf(p[d])) / TILE;
        int tile = (t[0]*NTPD + t[1])*NTPD + t[2];
        int idx = atomicAdd(&counts[tile], 1);
        if (idx < CAP) sorted[tile*CAP + idx] = make_float4(p[0], p[1], p[2], q);
    }
    #pragma unroll
    for (int o=32;o>0;o>>=1) { v += __shfl_down(v,o,64); v2 += __shfl_down(v2,o,64); }
    __shared__ float s1[4], s2[4];
    int lane = threadIdx.x & 63, w = threadIdx.x >> 6;
    if (lane==0) { s1[w]=v; s2[w]=v2; }
    __syncthreads();
    if (threadIdx.x==0) {
        for (int j=1;j<4;j++) { v += s1[j]; v2 += s2[j]; }
        atomicAdd(&acc[1], (double)v);
        atomicAdd(&acc[2], (double)v2);
    }
}

// TWO WAVES per tile; each wave accumulates its atoms into a private LDS copy
// with plain RMW on exclusively-owned (a,b) slices; merge at flush.
__global__ void __launch_bounds__(128)
spread_tile_kernel(const float4* __restrict__ sorted,
                   const int* __restrict__ counts,
                   float* __restrict__ buf) {
    int tile = blockIdx.x;
    int tx = tile / (NTPD*NTPD);
    int rem = tile - tx*NTPD*NTPD;
    int ty = rem / NTPD;
    int tz = rem - ty*NTPD;
    int bx = tx*TILE, by = ty*TILE, bz = tz*TILE;

    __shared__ float accS[2][FPCELLS];   // 39.3 KB
    __shared__ float W[128][18];         // 9.2 KB
    __shared__ int   baseS[128];

    int tid  = threadIdx.x;
    int wid  = tid >> 6;
    int lane = tid & 63;
    for (int i = tid; i < FPCELLS; i += 128) { accS[0][i] = 0.f; accS[1][i] = 0.f; }

    int a = lane / 6, b = lane - a*6;            // active for lane<36
    int laneoff = a*(FP*FP) + b*FP;

    int cntT = min(counts[tile], CAP);
    const float4* src = sorted + tile*CAP;

    for (int start = 0; start < cntT; start += 128) {
        int my = start + tid;
        if (my < cntT) {
            float4 s = src[my];
            float fx = floorf(s.x);
            float wx[6]; lag6(s.x - (fx + 0.5f), wx);
            float fy = floorf(s.y);
            float wy[6]; lag6(s.y - (fy + 0.5f), wy);
            float fz = floorf(s.z);
            float wz[6]; lag6(s.z - (fz + 0.5f), wz);
            int lx = wrap120((int)fx) - bx;
            int ly = wrap120((int)fy) - by;
            int lz = wrap120((int)fz) - bz;
            baseS[tid] = (lx*FP + ly)*FP + lz;
            #pragma unroll
            for (int k=0;k<6;++k) {
                W[tid][k]    = wx[k]*s.w;
                W[tid][6+k]  = wy[k];
                W[tid][12+k] = wz[k];
            }
        }
        __syncthreads();
        int jn = cntT - start - wid*64;
        jn = (jn > 64) ? 64 : jn;
        if (lane < 36) {
            for (int j = 0; j < jn; ++j) {
                int row = wid*64 + j;
                float w2 = W[row][a] * W[row][6+b];
                int ad = baseS[row] + laneoff;
                #pragma unroll
                for (int c=0;c<6;++c)
                    accS[wid][ad + c] += w2 * W[row][12+c];
            }
        }
        __syncthreads();
    }

    for (int i = tid; i < FPCELLS; i += 128)
        buf[(size_t)tile * FPSTRIDE + i] = accS[0][i] + accS[1][i];
}

// ---- radix-4 decimated 120-point DFT main loop (uniform for all stages) ----
// X[k] = sum_{j<30} Y[k&3][j] * W^{k*j};  2 strands (even/odd j) for ILP.
// Twiddle init via hw __sincosf (v_sin/v_cos) — f64 OCML sincos was a
// measured stall source at 2.6M calls.
#define DFT30_BODY(Yp, kfreq, RE, IM)                                        \
    float w1r, w1i;                                                          \
    __sincosf(-0.052359877559829887f * (float)(kfreq), &w1i, &w1r);          \
    float w2r = w1r*w1r - w1i*w1i, w2i = 2.f*w1r*w1i;                        \
    float ar=1.f, ai=0.f, br=w1r, bi=w1i;                                    \
    float r0_=0.f,i0_=0.f,r1_=0.f,i1_=0.f;                                   \
    _Pragma("unroll")                                                        \
    for (int s_=0;s_<15;++s_) {                                              \
        float2 ya = (Yp)[2*s_], yb = (Yp)[2*s_+1];                           \
        r0_ = fmaf(ya.x, ar, fmaf(-ya.y, ai, r0_));                          \
        i0_ = fmaf(ya.x, ai, fmaf( ya.y, ar, i0_));                          \
        r1_ = fmaf(yb.x, br, fmaf(-yb.y, bi, r1_));                          \
        i1_ = fmaf(yb.x, bi, fmaf( yb.y, br, i1_));                          \
        float nar = ar*w2r - ai*w2i, nai = ar*w2i + ai*w2r; ar=nar; ai=nai;  \
        float nbr = br*w2r - bi*w2i, nbi = br*w2i + bi*w2r; br=nbr; bi=nbi;  \
    }                                                                        \
    float RE = r0_+r1_, IM = i0_+i1_;

// stage 1: halo-gather + rfft along z (radix-4 pre-combine). out C1[x][kz][y].
__global__ void __launch_bounds__(256)
fft_z_kernel(const float* __restrict__ buf,
             float2* __restrict__ C1) {
    int x  = blockIdx.x / 10;
    int y0 = (blockIdx.x - x*10) * YCH;
    __shared__ float  lin[YCH][121];
    __shared__ float2 Y[YCH][4][31];     // padded: conflict-free reads

    int txA[2], lxA[2];
    int nx = halo_pairs(x, txA, lxA);

    for (int i = threadIdx.x; i < YCH*120; i += 256) {
        int yl = i / 120, z = i - yl*120;
        int tyA[2], lyA[2]; int ny = halo_pairs(y0 + yl, tyA, lyA);
        int tzA[2], lzA[2]; int nz = halo_pairs(z, tzA, lzA);
        float s = 0.f;
        for (int ii=0; ii<nx; ++ii)
            for (int jj=0; jj<ny; ++jj)
                for (int kk=0; kk<nz; ++kk) {
                    int tile = (txA[ii]*NTPD + tyA[jj])*NTPD + tzA[kk];
                    int cell = (lxA[ii]*FP + lyA[jj])*FP + lzA[kk];
                    s += buf[(size_t)tile*FPSTRIDE + cell];
                }
        lin[yl][z] = s;
    }
    __syncthreads();
    // radix-4 combine: z = 30m + j ; W^(30mk) = (-i)^(mk), real input
    for (int t = threadIdx.x; t < YCH*30; t += 256) {
        int yl = t / 30, j = t - (t/30)*30;
        float x0 = lin[yl][j], x1 = lin[yl][j+30], x2 = lin[yl][j+60], x3 = lin[yl][j+90];
        float s02 = x0+x2, d02 = x0-x2, s13 = x1+x3, d13 = x1-x3;
        Y[yl][0][j] = make_float2(s02+s13, 0.f);
        Y[yl][2][j] = make_float2(s02-s13, 0.f);
        Y[yl][1][j] = make_float2(d02, -d13);
        Y[yl][3][j] = make_float2(d02,  d13);
    }
    __syncthreads();
    for (int o = threadIdx.x; o < YCH*NKZ; o += 256) {
        int kz = o / YCH, yl = o - (o/YCH)*YCH;
        const float2* Yp = Y[yl][kz & 3];
        DFT30_BODY(Yp, kz, re, im)
        C1[(x*NKZ + kz)*120 + y0 + yl] = make_float2(re, im);
    }
}

// stage 2: cfft along y (radix-4). block = (4 consecutive x, kz). out C2[kz][ky][x].
__global__ void __launch_bounds__(256)
fft_y_kernel(const float2* __restrict__ C1,
             float2* __restrict__ C2) {
    int xc = blockIdx.x / NKZ;
    int kz = blockIdx.x - xc*NKZ;
    int x0 = xc * XCH;
    __shared__ float2 lin[XCH][121];
    __shared__ float2 Y[XCH][4][31];
    for (int i = threadIdx.x; i < XCH*120; i += 256) {
        int xo = i / 120, y = i - (i/120)*120;
        lin[xo][y] = C1[((x0+xo)*NKZ + kz)*120 + y];
    }
    __syncthreads();
    for (int t = threadIdx.x; t < XCH*30; t += 256) {
        int xo = t / 30, j = t - (t/30)*30;
        float2 a0 = lin[xo][j], a1 = lin[xo][j+30], a2 = lin[xo][j+60], a3 = lin[xo][j+90];
        float s02r=a0.x+a2.x, s02i=a0.y+a2.y, d02r=a0.x-a2.x, d02i=a0.y-a2.y;
        float s13r=a1.x+a3.x, s13i=a1.y+a3.y, d13r=a1.x-a3.x, d13i=a1.y-a3.y;
        Y[xo][0][j] = make_float2(s02r+s13r, s02i+s13i);
        Y[xo][2][j] = make_float2(s02r-s13r, s02i-s13i);
        Y[xo][1][j] = make_float2(d02r+d13i, d02i-d13r);
        Y[xo][3][j] = make_float2(d02r-d13i, d02i+d13r);
    }
    __syncthreads();
    for (int o = threadIdx.x; o < XCH*120; o += 256) {
        int ky = o >> 2, xo = o & 3;
        const float2* Yp = Y[xo][ky & 3];
        DFT30_BODY(Yp, ky, re, im)
        C2[(kz*120 + ky)*120 + x0 + xo] = make_float2(re, im);
    }
}

// stage 3: cfft along x (radix-4) + G-weighted energy reduction.
__global__ void __launch_bounds__(256)
fft_x_energy_kernel(const float2* __restrict__ C2,
                    const float* __restrict__ box,
                    double* __restrict__ acc) {
    int kyc = blockIdx.x / NKZ;
    int kz  = blockIdx.x - kyc*NKZ;
    int ky0 = kyc * XCH;
    __shared__ float2 lin[XCH][121];
    __shared__ float2 Y[XCH][4][31];
    const float2* src = C2 + (kz*120 + ky0)*120;
    for (int i = threadIdx.x; i < XCH*120; i += 256) {
        int kyo = i / 120, xx = i - (i/120)*120;
        lin[kyo][xx] = src[i];
    }
    __syncthreads();
    for (int t = threadIdx.x; t < XCH*30; t += 256) {
        int kyo = t / 30, j = t - (t/30)*30;
        float2 a0 = lin[kyo][j], a1 = lin[kyo][j+30], a2 = lin[kyo][j+60], a3 = lin[kyo][j+90];
        float s02r=a0.x+a2.x, s02i=a0.y+a2.y, d02r=a0.x-a2.x, d02i=a0.y-a2.y;
        float s13r=a1.x+a3.x, s13i=a1.y+a3.y, d13r=a1.x-a3.x, d13i=a1.y-a3.y;
        Y[kyo][0][j] = make_float2(s02r+s13r, s02i+s13i);
        Y[kyo][2][j] = make_float2(s02r-s13r, s02i-s13i);
        Y[kyo][1][j] = make_float2(d02r+d13i, d02i-d13r);
        Y[kyo][3][j] = make_float2(d02r-d13i, d02i+d13r);
    }
    __syncthreads();
    float ib[9]; inv3(box, ib);
    const float TWOPI = 6.283185307179586f;
    float wzf = (kz==0 || kz==60) ? 1.0f : 2.0f;
    float contrib = 0.f;
    for (int o = threadIdx.x; o < XCH*120; o += 256) {
        int kyo = o / 120, kx = o - (o/120)*120;
        int ky = ky0 + kyo;
        const float2* Yp = Y[kyo][kx & 3];
        DFT30_BODY(Yp, kx, re, im)
        if (!(kx==0 && ky==0 && kz==0)) {
            float mx = (kx < 60) ? (float)kx : (float)(kx - 120);
            float my = (ky < 60) ? (float)ky : (float)(ky - 120);
            float mz = (float)kz;
            float k0 = TWOPI*(mx*ib[0] + my*ib[1] + mz*ib[2]);
            float k1 = TWOPI*(mx*ib[3] + my*ib[4] + mz*ib[5]);
            float k2 = TWOPI*(mx*ib[6] + my*ib[7] + mz*ib[8]);
            float ksq = k0*k0 + k1*k1 + k2*k2;
            float G = 12.566370614359172f * __expf(-0.5f*(float)(ALPHA_C*ALPHA_C)*ksq) / ksq;
            contrib += wzf * G * (re*re + im*im);
        }
    }
    #pragma unroll
    for (int o=32;o>0;o>>=1) contrib += __shfl_down(contrib,o,64);
    __shared__ float sm[4];
    int lane = threadIdx.x & 63, w = threadIdx.x >> 6;
    if (lane==0) sm[w] = contrib;
    __syncthreads();
    if (threadIdx.x==0)
        atomicAdd(&acc[0], (double)(sm[0]+sm[1]+sm[2]+sm[3]));
}

__global__ void finalize_kernel(const double* __restrict__ acc,
                                const float* __restrict__ box,
                                float* __restrict__ out) {
    double ek = acc[0], sq = acc[1], sq2 = acc[2];
    double a00=box[0],a01=box[1],a02=box[2],a10=box[3],a11=box[4],a12=box[5],a20=box[6],a21=box[7],a22=box[8];
    double det = a00*(a11*a22-a12*a21) - a01*(a10*a22-a12*a20) + a02*(a10*a21-a11*a20);
    double vol = fabs(det);
    double E = ek/(2.0*vol)
             - 0.5*sqrt(2.0/M_PI)/ALPHA_C * sq2
             - M_PI*ALPHA_C*ALPHA_C * sq*sq / vol;
    out[0] = (float)E;
}

extern "C" void kernel_launch(void* const* d_in, const int* in_sizes, int n_in,
                              void* d_out, int out_size, void* d_ws, size_t ws_size,
                              hipStream_t stream) {
    const float* coords  = (const float*)d_in[0];
    const float* box     = (const float*)d_in[1];
    const float* charges = (const float*)d_in[2];
    int n = in_sizes[0] / 3;

    char* ws = (char*)d_ws;
    double* acc     = (double*)(ws + ACC_OFF);
    float*  buf     = (float*) (ws + BUF_OFF);
    float2* C1      = (float2*)(ws + C1_OFF);
    float2* C2      = (float2*)(ws + C2_OFF);
    int* counts     = (int*)(ws + COUNTS_OFF);
    float4* sorted  = (float4*)(ws + SORTED_OFF);

    int gA = (n + 255)/256;
    init_kernel<<<1, 1024, 0, stream>>>(counts, acc);
    scatter_q_kernel<<<gA, 256, 0, stream>>>(coords, box, charges, counts, sorted, acc, n);
    spread_tile_kernel<<<NTILE, 128, 0, stream>>>(sorted, counts, buf);
    fft_z_kernel<<<120*10, 256, 0, stream>>>(buf, C1);
    fft_y_kernel<<<30*NKZ, 256, 0, stream>>>(C1, C2);
    fft_x_energy_kernel<<<NKZ*30, 256, 0, stream>>>(C2, box, acc);
    finalize_kernel<<<1, 1, 0, stream>>>(acc, box, (float*)d_out);
}

// Round 13
// 162.522 us; speedup vs baseline: 1.4867x; 1.1325x over previous
//
#include <hip/hip_runtime.h>
#include <math.h>

#define NMESH 120
#define NKZ 61            // rfft half-spectrum along z
#define NTOT (120*120*120)
#define ALPHA_C 1.0

#define TILE 12           // mesh cells per tile per dim
#define NTPD 10           // tiles per dim
#define NTILE 1000
#define FP 17             // footprint per dim: TILE + 5
#define FPCELLS (FP*FP*FP)   // 4913
#define FPSTRIDE 4928        // padded tile stride (buf layout, unchanged)
#define SA 292               // LDS accS a-stride: banks (4a+17b)%32 -> max 2-way (free)
#define SACC 4961            // per-copy accS size: 16*292+16*17+16+1
#define CAP 256              // bucket capacity (Poisson(100): overflow ~1e-40)

#define YCH 12            // y-lines per fft_z block (1200 blocks)
#define XCH 4             // x per fft_y block / ky per fft_x block

#define NSLOT 64          // accumulator slots (64B apart) to kill same-address atomic serialization
#define SLOTSTRIDE 8      // doubles per slot

// ---- workspace layout (bytes) ----
// [0, 4096)      : double ekslots[64*8]   (slot stride 64B)
// [4096, 8192)   : double qslots [64*8]
// [8192, 12288)  : double q2slots[64*8]
// [115264, +19712000)  : float buf[1000][4928] tile footprints
// [19827264, +7027200) : float2 C1[x][kz][y]
//    counts + CAP-padded sorted atoms ALIAS the C1 region (dead before fft_z writes C1)
// C2[kz][ky][x] ALIASES buf (buf dead after fft_z)
#define EK_OFF      0
#define Q_OFF       4096
#define Q2_OFF      8192
#define BUF_OFF     115264
#define C1_OFF      19827264
#define C2_OFF      115264
#define COUNTS_OFF  C1_OFF
#define SORTED_OFF  (C1_OFF + 4096)      // 1000*256*16 = 4.096 MB < 7 MB region

__device__ inline void inv3(const float* b, float* ib) {
    float a00=b[0],a01=b[1],a02=b[2],a10=b[3],a11=b[4],a12=b[5],a20=b[6],a21=b[7],a22=b[8];
    float c00 =  a11*a22 - a12*a21;
    float c01 = -(a10*a22 - a12*a20);
    float c02 =  a10*a21 - a11*a20;
    float c10 = -(a01*a22 - a02*a21);
    float c11 =  a00*a22 - a02*a20;
    float c12 = -(a00*a21 - a01*a20);
    float c20 =  a01*a12 - a02*a11;
    float c21 = -(a00*a12 - a02*a10);
    float c22 =  a00*a11 - a01*a10;
    float det = a00*c00 + a01*c01 + a02*c02;
    float inv = 1.0f/det;
    ib[0]=c00*inv; ib[1]=c10*inv; ib[2]=c20*inv;
    ib[3]=c01*inv; ib[4]=c11*inv; ib[5]=c21*inv;
    ib[6]=c02*inv; ib[7]=c12*inv; ib[8]=c22*inv;
}

__device__ inline void atom_pos(const float* __restrict__ box, float c0, float c1, float c2,
                                float* p) {
    float ib[9]; inv3(box, ib);
    #pragma unroll
    for (int d=0; d<3; ++d)
        p[d] = (c0*ib[0+d] + c1*ib[3+d] + c2*ib[6+d]) * 120.0f;
}

__device__ inline int wrap120(int i) { return ((i % 120) + 120) % 120; }

// order-6 Lagrange weights; x = pos - (floor(pos)+0.5)
__device__ inline void lag6(float x, float* w) {
    float df[6];
    #pragma unroll
    for (int k=0;k<6;++k) df[k] = x - ((float)k - 2.5f);
    w[0] = df[1]*df[2]*df[3]*df[4]*df[5] * (-1.0f/120.0f);
    w[1] = df[0]*df[2]*df[3]*df[4]*df[5] * ( 1.0f/24.0f);
    w[2] = df[0]*df[1]*df[3]*df[4]*df[5] * (-1.0f/12.0f);
    w[3] = df[0]*df[1]*df[2]*df[4]*df[5] * ( 1.0f/12.0f);
    w[4] = df[0]*df[1]*df[2]*df[3]*df[5] * (-1.0f/24.0f);
    w[5] = df[0]*df[1]*df[2]*df[3]*df[4] * ( 1.0f/120.0f);
}

// per-dim halo decomposition: cell c -> up to 2 (tile, local) pairs
__device__ inline int halo_pairs(int c, int* t, int* l) {
    int r = c % 12, ti = c / 12, n = 0;
    t[n] = ti;          l[n] = r + 2;  n++;
    if (r < 3)  { t[n] = (ti+9)%10; l[n] = r + 14; n++; }
    if (r >= 10){ t[n] = (ti+1)%10; l[n] = r - 10; n++; }
    return n;
}

__global__ void init_kernel(int* __restrict__ counts, double* __restrict__ slots) {
    int idx = threadIdx.x;
    for (int i = idx; i < 3*NSLOT*SLOTSTRIDE; i += 1024) slots[i] = 0.0;
    for (int i = idx; i < NTILE; i += 1024) counts[i] = 0;
}

// one-pass bucket scatter + sum(q) + sum(q^2) into per-slot accumulators
__global__ void scatter_q_kernel(const float* __restrict__ coords,
                                 const float* __restrict__ box,
                                 const float* __restrict__ charges,
                                 int* __restrict__ counts,
                                 float4* __restrict__ sorted,
                                 double* __restrict__ qslots,
                                 double* __restrict__ q2slots, int n) {
    int i = blockIdx.x*blockDim.x + threadIdx.x;
    float v = 0.f, v2 = 0.f;
    if (i < n) {
        float p[3]; atom_pos(box, coords[3*i], coords[3*i+1], coords[3*i+2], p);
        float q = charges[i];
        v = q; v2 = q*q;
        int t[3];
        #pragma unroll
        for (int d=0; d<3; ++d) t[d] = wrap120((int)floorf(p[d])) / TILE;
        int tile = (t[0]*NTPD + t[1])*NTPD + t[2];
        int idx = atomicAdd(&counts[tile], 1);
        if (idx < CAP) sorted[tile*CAP + idx] = make_float4(p[0], p[1], p[2], q);
    }
    #pragma unroll
    for (int o=32;o>0;o>>=1) { v += __shfl_down(v,o,64); v2 += __shfl_down(v2,o,64); }
    __shared__ float s1[4], s2[4];
    int lane = threadIdx.x & 63, w = threadIdx.x >> 6;
    if (lane==0) { s1[w]=v; s2[w]=v2; }
    __syncthreads();
    if (threadIdx.x==0) {
        for (int j=1;j<4;j++) { v += s1[j]; v2 += s2[j]; }
        int slot = (blockIdx.x & (NSLOT-1)) * SLOTSTRIDE;
        atomicAdd(&qslots[slot],  (double)v);
        atomicAdd(&q2slots[slot], (double)v2);
    }
}

// TWO WAVES per tile; plain LDS RMW on exclusively-owned (a,b) slices.
// accS a-stride = 292 -> bank pattern (4a+17b)%32, max 2-way (free).
__global__ void __launch_bounds__(128)
spread_tile_kernel(const float4* __restrict__ sorted,
                   const int* __restrict__ counts,
                   float* __restrict__ buf) {
    int tile = blockIdx.x;
    int tx = tile / (NTPD*NTPD);
    int rem = tile - tx*NTPD*NTPD;
    int ty = rem / NTPD;
    int tz = rem - ty*NTPD;
    int bx = tx*TILE, by = ty*TILE, bz = tz*TILE;

    __shared__ float accS[2][SACC];      // 39.7 KB
    __shared__ float W[128][18];         // 9.2 KB
    __shared__ int   baseS[128];

    int tid  = threadIdx.x;
    int wid  = tid >> 6;
    int lane = tid & 63;
    for (int i = tid; i < SACC; i += 128) { accS[0][i] = 0.f; accS[1][i] = 0.f; }

    int a = lane / 6, b = lane - a*6;            // active for lane<36
    int laneoff = a*SA + b*FP;

    int cntT = min(counts[tile], CAP);
    const float4* src = sorted + tile*CAP;

    for (int start = 0; start < cntT; start += 128) {
        int my = start + tid;
        if (my < cntT) {
            float4 s = src[my];
            float fx = floorf(s.x);
            float wx[6]; lag6(s.x - (fx + 0.5f), wx);
            float fy = floorf(s.y);
            float wy[6]; lag6(s.y - (fy + 0.5f), wy);
            float fz = floorf(s.z);
            float wz[6]; lag6(s.z - (fz + 0.5f), wz);
            int lx = wrap120((int)fx) - bx;
            int ly = wrap120((int)fy) - by;
            int lz = wrap120((int)fz) - bz;
            baseS[tid] = lx*SA + ly*FP + lz;
            #pragma unroll
            for (int k=0;k<6;++k) {
                W[tid][k]    = wx[k]*s.w;
                W[tid][6+k]  = wy[k];
                W[tid][12+k] = wz[k];
            }
        }
        __syncthreads();
        int jn = cntT - start - wid*64;
        jn = (jn > 64) ? 64 : jn;
        if (lane < 36) {
            for (int j = 0; j < jn; ++j) {
                int row = wid*64 + j;
                float w2 = W[row][a] * W[row][6+b];
                int ad = baseS[row] + laneoff;
                #pragma unroll
                for (int c=0;c<6;++c)
                    accS[wid][ad + c] += w2 * W[row][12+c];
            }
        }
        __syncthreads();
    }

    // flush: remap padded accS index -> buf's dense (lx*17+ly)*17+lz layout
    for (int i = tid; i < FPCELLS; i += 128) {
        int lx = i / (FP*FP);
        int r  = i - lx*FP*FP;
        int ly = r / FP;
        int lz = r - ly*FP;
        int ai = lx*SA + ly*FP + lz;
        buf[(size_t)tile * FPSTRIDE + i] = accS[0][ai] + accS[1][ai];
    }
}

// ---- radix-4 decimated 120-point DFT main loop (uniform for all stages) ----
// X[k] = sum_{j<30} Y[k&3][j] * W^{k*j};  2 strands (even/odd j) for ILP.
#define DFT30_BODY(Yp, kfreq, RE, IM)                                        \
    float w1r, w1i;                                                          \
    __sincosf(-0.052359877559829887f * (float)(kfreq), &w1i, &w1r);          \
    float w2r = w1r*w1r - w1i*w1i, w2i = 2.f*w1r*w1i;                        \
    float ar=1.f, ai=0.f, br=w1r, bi=w1i;                                    \
    float r0_=0.f,i0_=0.f,r1_=0.f,i1_=0.f;                                   \
    _Pragma("unroll")                                                        \
    for (int s_=0;s_<15;++s_) {                                              \
        float2 ya = (Yp)[2*s_], yb = (Yp)[2*s_+1];                           \
        r0_ = fmaf(ya.x, ar, fmaf(-ya.y, ai, r0_));                          \
        i0_ = fmaf(ya.x, ai, fmaf( ya.y, ar, i0_));                          \
        r1_ = fmaf(yb.x, br, fmaf(-yb.y, bi, r1_));                          \
        i1_ = fmaf(yb.x, bi, fmaf( yb.y, br, i1_));                          \
        float nar = ar*w2r - ai*w2i, nai = ar*w2i + ai*w2r; ar=nar; ai=nai;  \
        float nbr = br*w2r - bi*w2i, nbi = br*w2i + bi*w2r; br=nbr; bi=nbi;  \
    }                                                                        \
    float RE = r0_+r1_, IM = i0_+i1_;

// stage 1: halo-gather + rfft along z (radix-4 pre-combine). out C1[x][kz][y].
__global__ void __launch_bounds__(256)
fft_z_kernel(const float* __restrict__ buf,
             float2* __restrict__ C1) {
    int x  = blockIdx.x / 10;
    int y0 = (blockIdx.x - x*10) * YCH;
    __shared__ float  lin[YCH][121];
    __shared__ float2 Y[YCH][4][31];     // padded: conflict-free reads

    int txA[2], lxA[2];
    int nx = halo_pairs(x, txA, lxA);

    for (int i = threadIdx.x; i < YCH*120; i += 256) {
        int yl = i / 120, z = i - yl*120;
        int tyA[2], lyA[2]; int ny = halo_pairs(y0 + yl, tyA, lyA);
        int tzA[2], lzA[2]; int nz = halo_pairs(z, tzA, lzA);
        float s = 0.f;
        for (int ii=0; ii<nx; ++ii)
            for (int jj=0; jj<ny; ++jj)
                for (int kk=0; kk<nz; ++kk) {
                    int tile = (txA[ii]*NTPD + tyA[jj])*NTPD + tzA[kk];
                    int cell = (lxA[ii]*FP + lyA[jj])*FP + lzA[kk];
                    s += buf[(size_t)tile*FPSTRIDE + cell];
                }
        lin[yl][z] = s;
    }
    __syncthreads();
    // radix-4 combine: z = 30m + j ; W^(30mk) = (-i)^(mk), real input
    for (int t = threadIdx.x; t < YCH*30; t += 256) {
        int yl = t / 30, j = t - (t/30)*30;
        float x0 = lin[yl][j], x1 = lin[yl][j+30], x2 = lin[yl][j+60], x3 = lin[yl][j+90];
        float s02 = x0+x2, d02 = x0-x2, s13 = x1+x3, d13 = x1-x3;
        Y[yl][0][j] = make_float2(s02+s13, 0.f);
        Y[yl][2][j] = make_float2(s02-s13, 0.f);
        Y[yl][1][j] = make_float2(d02, -d13);
        Y[yl][3][j] = make_float2(d02,  d13);
    }
    __syncthreads();
    for (int o = threadIdx.x; o < YCH*NKZ; o += 256) {
        int kz = o / YCH, yl = o - (o/YCH)*YCH;
        const float2* Yp = Y[yl][kz & 3];
        DFT30_BODY(Yp, kz, re, im)
        C1[(x*NKZ + kz)*120 + y0 + yl] = make_float2(re, im);
    }
}

// stage 2: cfft along y (radix-4). block = (4 consecutive x, kz). out C2[kz][ky][x].
__global__ void __launch_bounds__(256)
fft_y_kernel(const float2* __restrict__ C1,
             float2* __restrict__ C2) {
    int xc = blockIdx.x / NKZ;
    int kz = blockIdx.x - xc*NKZ;
    int x0 = xc * XCH;
    __shared__ float2 lin[XCH][121];
    __shared__ float2 Y[XCH][4][31];
    for (int i = threadIdx.x; i < XCH*120; i += 256) {
        int xo = i / 120, y = i - (i/120)*120;
        lin[xo][y] = C1[((x0+xo)*NKZ + kz)*120 + y];
    }
    __syncthreads();
    for (int t = threadIdx.x; t < XCH*30; t += 256) {
        int xo = t / 30, j = t - (t/30)*30;
        float2 a0 = lin[xo][j], a1 = lin[xo][j+30], a2 = lin[xo][j+60], a3 = lin[xo][j+90];
        float s02r=a0.x+a2.x, s02i=a0.y+a2.y, d02r=a0.x-a2.x, d02i=a0.y-a2.y;
        float s13r=a1.x+a3.x, s13i=a1.y+a3.y, d13r=a1.x-a3.x, d13i=a1.y-a3.y;
        Y[xo][0][j] = make_float2(s02r+s13r, s02i+s13i);
        Y[xo][2][j] = make_float2(s02r-s13r, s02i-s13i);
        Y[xo][1][j] = make_float2(d02r+d13i, d02i-d13r);
        Y[xo][3][j] = make_float2(d02r-d13i, d02i+d13r);
    }
    __syncthreads();
    for (int o = threadIdx.x; o < XCH*120; o += 256) {
        int ky = o >> 2, xo = o & 3;
        const float2* Yp = Y[xo][ky & 3];
        DFT30_BODY(Yp, ky, re, im)
        C2[(kz*120 + ky)*120 + x0 + xo] = make_float2(re, im);
    }
}

// stage 3: cfft along x (radix-4) + G-weighted energy reduction (slotted atomic).
__global__ void __launch_bounds__(256)
fft_x_energy_kernel(const float2* __restrict__ C2,
                    const float* __restrict__ box,
                    double* __restrict__ ekslots) {
    int kyc = blockIdx.x / NKZ;
    int kz  = blockIdx.x - kyc*NKZ;
    int ky0 = kyc * XCH;
    __shared__ float2 lin[XCH][121];
    __shared__ float2 Y[XCH][4][31];
    const float2* src = C2 + (kz*120 + ky0)*120;
    for (int i = threadIdx.x; i < XCH*120; i += 256) {
        int kyo = i / 120, xx = i - (i/120)*120;
        lin[kyo][xx] = src[i];
    }
    __syncthreads();
    for (int t = threadIdx.x; t < XCH*30; t += 256) {
        int kyo = t / 30, j = t - (t/30)*30;
        float2 a0 = lin[kyo][j], a1 = lin[kyo][j+30], a2 = lin[kyo][j+60], a3 = lin[kyo][j+90];
        float s02r=a0.x+a2.x, s02i=a0.y+a2.y, d02r=a0.x-a2.x, d02i=a0.y-a2.y;
        float s13r=a1.x+a3.x, s13i=a1.y+a3.y, d13r=a1.x-a3.x, d13i=a1.y-a3.y;
        Y[kyo][0][j] = make_float2(s02r+s13r, s02i+s13i);
        Y[kyo][2][j] = make_float2(s02r-s13r, s02i-s13i);
        Y[kyo][1][j] = make_float2(d02r+d13i, d02i-d13r);
        Y[kyo][3][j] = make_float2(d02r-d13i, d02i+d13r);
    }
    __syncthreads();
    float ib[9]; inv3(box, ib);
    const float TWOPI = 6.283185307179586f;
    float wzf = (kz==0 || kz==60) ? 1.0f : 2.0f;
    float contrib = 0.f;
    for (int o = threadIdx.x; o < XCH*120; o += 256) {
        int kyo = o / 120, kx = o - (o/120)*120;
        int ky = ky0 + kyo;
        const float2* Yp = Y[kyo][kx & 3];
        DFT30_BODY(Yp, kx, re, im)
        if (!(kx==0 && ky==0 && kz==0)) {
            float mx = (kx < 60) ? (float)kx : (float)(kx - 120);
            float my = (ky < 60) ? (float)ky : (float)(ky - 120);
            float mz = (float)kz;
            float k0 = TWOPI*(mx*ib[0] + my*ib[1] + mz*ib[2]);
            float k1 = TWOPI*(mx*ib[3] + my*ib[4] + mz*ib[5]);
            float k2 = TWOPI*(mx*ib[6] + my*ib[7] + mz*ib[8]);
            float ksq = k0*k0 + k1*k1 + k2*k2;
            float G = 12.566370614359172f * __expf(-0.5f*(float)(ALPHA_C*ALPHA_C)*ksq) / ksq;
            contrib += wzf * G * (re*re + im*im);
        }
    }
    #pragma unroll
    for (int o=32;o>0;o>>=1) contrib += __shfl_down(contrib,o,64);
    __shared__ float sm[4];
    int lane = threadIdx.x & 63, w = threadIdx.x >> 6;
    if (lane==0) sm[w] = contrib;
    __syncthreads();
    if (threadIdx.x==0)
        atomicAdd(&ekslots[(blockIdx.x & (NSLOT-1)) * SLOTSTRIDE],
                  (double)(sm[0]+sm[1]+sm[2]+sm[3]));
}

// 64-lane slot reduction + closed-form corrections
__global__ void finalize_kernel(const double* __restrict__ ekslots,
                                const double* __restrict__ qslots,
                                const double* __restrict__ q2slots,
                                const float* __restrict__ box,
                                float* __restrict__ out) {
    int lane = threadIdx.x;
    double ek  = ekslots[lane*SLOTSTRIDE];
    double sq  = qslots [lane*SLOTSTRIDE];
    double sq2 = q2slots[lane*SLOTSTRIDE];
    #pragma unroll
    for (int o=32;o>0;o>>=1) {
        ek  += __shfl_down(ek,  o, 64);
        sq  += __shfl_down(sq,  o, 64);
        sq2 += __shfl_down(sq2, o, 64);
    }
    if (lane == 0) {
        double a00=box[0],a01=box[1],a02=box[2],a10=box[3],a11=box[4],a12=box[5],a20=box[6],a21=box[7],a22=box[8];
        double det = a00*(a11*a22-a12*a21) - a01*(a10*a22-a12*a20) + a02*(a10*a21-a11*a20);
        double vol = fabs(det);
        double E = ek/(2.0*vol)
                 - 0.5*sqrt(2.0/M_PI)/ALPHA_C * sq2
                 - M_PI*ALPHA_C*ALPHA_C * sq*sq / vol;
        out[0] = (float)E;
    }
}

extern "C" void kernel_launch(void* const* d_in, const int* in_sizes, int n_in,
                              void* d_out, int out_size, void* d_ws, size_t ws_size,
                              hipStream_t stream) {
    const float* coords  = (const float*)d_in[0];
    const float* box     = (const float*)d_in[1];
    const float* charges = (const float*)d_in[2];
    int n = in_sizes[0] / 3;

    char* ws = (char*)d_ws;
    double* ekslots = (double*)(ws + EK_OFF);
    double* qslots  = (double*)(ws + Q_OFF);
    double* q2slots = (double*)(ws + Q2_OFF);
    float*  buf     = (float*) (ws + BUF_OFF);
    float2* C1      = (float2*)(ws + C1_OFF);
    float2* C2      = (float2*)(ws + C2_OFF);
    int* counts     = (int*)(ws + COUNTS_OFF);
    float4* sorted  = (float4*)(ws + SORTED_OFF);

    int gA = (n + 255)/256;
    init_kernel<<<1, 1024, 0, stream>>>(counts, ekslots);
    scatter_q_kernel<<<gA, 256, 0, stream>>>(coords, box, charges, counts, sorted, qslots, q2slots, n);
    spread_tile_kernel<<<NTILE, 128, 0, stream>>>(sorted, counts, buf);
    fft_z_kernel<<<120*10, 256, 0, stream>>>(buf, C1);
    fft_y_kernel<<<30*NKZ, 256, 0, stream>>>(C1, C2);
    fft_x_energy_kernel<<<NKZ*30, 256, 0, stream>>>(C2, box, ekslots);
    finalize_kernel<<<1, 64, 0, stream>>>(ekslots, qslots, q2slots, box, (float*)d_out);
}

// Round 14
// 152.110 us; speedup vs baseline: 1.5885x; 1.0685x over previous
//
#include <hip/hip_runtime.h>
#include <math.h>

#define NMESH 120
#define NKZ 61            // rfft half-spectrum along z
#define NTOT (120*120*120)
#define ALPHA_C 1.0

#define TILE 12           // mesh cells per tile per dim
#define NTPD 10           // tiles per dim
#define NTILE 1000
#define FP 17             // footprint per dim: TILE + 5
#define FPCELLS (FP*FP*FP)   // 4913
#define FPSTRIDE 4928        // padded tile stride (buf layout)
#define SA 292               // LDS accS a-stride: banks (4a+17b)%32 -> max 2-way (free)
#define SACC 4961            // per-copy accS size
#define CAP 256              // bucket capacity (Poisson(100): overflow ~1e-40)

#define YCH 12            // y-lines per fft_z block (1200 blocks)
#define XCH 4             // x per fft_y block / ky per fft_x block
#define YROW 137          // per-line Y storage: 8 rows * 17 + 1 pad (float2)

#define NSLOT 64          // accumulator slots (64B apart)
#define SLOTSTRIDE 8      // doubles per slot

// ---- workspace layout (bytes) ----
// [0, 4096)      : double ekslots[64*8]
// [4096, 8192)   : double qslots [64*8]
// [8192, 12288)  : double q2slots[64*8]
// [115264, +19712000)  : float buf[1000][4928] tile footprints
// [19827264, +7027200) : float2 C1[x][kz][y]
//    counts + CAP-padded sorted atoms ALIAS the C1 region (dead before fft_z writes C1)
// C2[kz][ky][x] ALIASES buf (buf dead after fft_z)
#define EK_OFF      0
#define Q_OFF       4096
#define Q2_OFF      8192
#define BUF_OFF     115264
#define C1_OFF      19827264
#define C2_OFF      115264
#define COUNTS_OFF  C1_OFF
#define SORTED_OFF  (C1_OFF + 4096)

__device__ inline void inv3(const float* b, float* ib) {
    float a00=b[0],a01=b[1],a02=b[2],a10=b[3],a11=b[4],a12=b[5],a20=b[6],a21=b[7],a22=b[8];
    float c00 =  a11*a22 - a12*a21;
    float c01 = -(a10*a22 - a12*a20);
    float c02 =  a10*a21 - a11*a20;
    float c10 = -(a01*a22 - a02*a21);
    float c11 =  a00*a22 - a02*a20;
    float c12 = -(a00*a21 - a01*a20);
    float c20 =  a01*a12 - a02*a11;
    float c21 = -(a00*a12 - a02*a10);
    float c22 =  a00*a11 - a01*a10;
    float det = a00*c00 + a01*c01 + a02*c02;
    float inv = 1.0f/det;
    ib[0]=c00*inv; ib[1]=c10*inv; ib[2]=c20*inv;
    ib[3]=c01*inv; ib[4]=c11*inv; ib[5]=c21*inv;
    ib[6]=c02*inv; ib[7]=c12*inv; ib[8]=c22*inv;
}

__device__ inline void atom_pos(const float* __restrict__ box, float c0, float c1, float c2,
                                float* p) {
    float ib[9]; inv3(box, ib);
    #pragma unroll
    for (int d=0; d<3; ++d)
        p[d] = (c0*ib[0+d] + c1*ib[3+d] + c2*ib[6+d]) * 120.0f;
}

__device__ inline int wrap120(int i) { return ((i % 120) + 120) % 120; }

// order-6 Lagrange weights; x = pos - (floor(pos)+0.5)
__device__ inline void lag6(float x, float* w) {
    float df[6];
    #pragma unroll
    for (int k=0;k<6;++k) df[k] = x - ((float)k - 2.5f);
    w[0] = df[1]*df[2]*df[3]*df[4]*df[5] * (-1.0f/120.0f);
    w[1] = df[0]*df[2]*df[3]*df[4]*df[5] * ( 1.0f/24.0f);
    w[2] = df[0]*df[1]*df[3]*df[4]*df[5] * (-1.0f/12.0f);
    w[3] = df[0]*df[1]*df[2]*df[4]*df[5] * ( 1.0f/12.0f);
    w[4] = df[0]*df[1]*df[2]*df[3]*df[5] * (-1.0f/24.0f);
    w[5] = df[0]*df[1]*df[2]*df[3]*df[4] * ( 1.0f/120.0f);
}

// per-dim halo decomposition: cell c -> up to 2 (tile, local) pairs
__device__ inline int halo_pairs(int c, int* t, int* l) {
    int r = c % 12, ti = c / 12, n = 0;
    t[n] = ti;          l[n] = r + 2;  n++;
    if (r < 3)  { t[n] = (ti+9)%10; l[n] = r + 14; n++; }
    if (r >= 10){ t[n] = (ti+1)%10; l[n] = r - 10; n++; }
    return n;
}

// 8-point DFT, complex in (m-order), complex out (k-order). W8 = e^{-2pi i/8}.
__device__ inline void dft8(const float2* xin, float2* Y) {
    const float S = 0.70710678118654752f;
    float2 a=xin[0], b=xin[2], c=xin[4], d=xin[6];
    float s02r=a.x+c.x, s02i=a.y+c.y, d02r=a.x-c.x, d02i=a.y-c.y;
    float s13r=b.x+d.x, s13i=b.y+d.y, d13r=b.x-d.x, d13i=b.y-d.y;
    float2 E0 = make_float2(s02r+s13r, s02i+s13i);
    float2 E1 = make_float2(d02r+d13i, d02i-d13r);   // d02 - i*d13
    float2 E2 = make_float2(s02r-s13r, s02i-s13i);
    float2 E3 = make_float2(d02r-d13i, d02i+d13r);
    a=xin[1]; b=xin[3]; c=xin[5]; d=xin[7];
    s02r=a.x+c.x; s02i=a.y+c.y; d02r=a.x-c.x; d02i=a.y-c.y;
    s13r=b.x+d.x; s13i=b.y+d.y; d13r=b.x-d.x; d13i=b.y-d.y;
    float2 O0 = make_float2(s02r+s13r, s02i+s13i);
    float2 O1 = make_float2(d02r+d13i, d02i-d13r);
    float2 O2 = make_float2(s02r-s13r, s02i-s13i);
    float2 O3 = make_float2(d02r-d13i, d02i+d13r);
    float t1r = S*(O1.x + O1.y), t1i = S*(O1.y - O1.x);   // W8^1 * O1
    float t2r = O2.y,            t2i = -O2.x;             // W8^2 = -i
    float t3r = S*(O3.y - O3.x), t3i = -S*(O3.x + O3.y);  // W8^3
    Y[0] = make_float2(E0.x + O0.x, E0.y + O0.y);
    Y[4] = make_float2(E0.x - O0.x, E0.y - O0.y);
    Y[1] = make_float2(E1.x + t1r,  E1.y + t1i);
    Y[5] = make_float2(E1.x - t1r,  E1.y - t1i);
    Y[2] = make_float2(E2.x + t2r,  E2.y + t2i);
    Y[6] = make_float2(E2.x - t2r,  E2.y - t2i);
    Y[3] = make_float2(E3.x + t3r,  E3.y + t3i);
    Y[7] = make_float2(E3.x - t3r,  E3.y - t3i);
}

__global__ void init_kernel(int* __restrict__ counts, double* __restrict__ slots) {
    int idx = threadIdx.x;
    for (int i = idx; i < 3*NSLOT*SLOTSTRIDE; i += 1024) slots[i] = 0.0;
    for (int i = idx; i < NTILE; i += 1024) counts[i] = 0;
}

// one-pass bucket scatter + sum(q) + sum(q^2) into per-slot accumulators
__global__ void scatter_q_kernel(const float* __restrict__ coords,
                                 const float* __restrict__ box,
                                 const float* __restrict__ charges,
                                 int* __restrict__ counts,
                                 float4* __restrict__ sorted,
                                 double* __restrict__ qslots,
                                 double* __restrict__ q2slots, int n) {
    int i = blockIdx.x*blockDim.x + threadIdx.x;
    float v = 0.f, v2 = 0.f;
    if (i < n) {
        float p[3]; atom_pos(box, coords[3*i], coords[3*i+1], coords[3*i+2], p);
        float q = charges[i];
        v = q; v2 = q*q;
        int t[3];
        #pragma unroll
        for (int d=0; d<3; ++d) t[d] = wrap120((int)floorf(p[d])) / TILE;
        int tile = (t[0]*NTPD + t[1])*NTPD + t[2];
        int idx = atomicAdd(&counts[tile], 1);
        if (idx < CAP) sorted[tile*CAP + idx] = make_float4(p[0], p[1], p[2], q);
    }
    #pragma unroll
    for (int o=32;o>0;o>>=1) { v += __shfl_down(v,o,64); v2 += __shfl_down(v2,o,64); }
    __shared__ float s1[4], s2[4];
    int lane = threadIdx.x & 63, w = threadIdx.x >> 6;
    if (lane==0) { s1[w]=v; s2[w]=v2; }
    __syncthreads();
    if (threadIdx.x==0) {
        for (int j=1;j<4;j++) { v += s1[j]; v2 += s2[j]; }
        int slot = (blockIdx.x & (NSLOT-1)) * SLOTSTRIDE;
        atomicAdd(&qslots[slot],  (double)v);
        atomicAdd(&q2slots[slot], (double)v2);
    }
}

// TWO WAVES per tile; plain LDS RMW on exclusively-owned (a,b) slices.
__global__ void __launch_bounds__(128)
spread_tile_kernel(const float4* __restrict__ sorted,
                   const int* __restrict__ counts,
                   float* __restrict__ buf) {
    int tile = blockIdx.x;
    int tx = tile / (NTPD*NTPD);
    int rem = tile - tx*NTPD*NTPD;
    int ty = rem / NTPD;
    int tz = rem - ty*NTPD;
    int bx = tx*TILE, by = ty*TILE, bz = tz*TILE;

    __shared__ float accS[2][SACC];
    __shared__ float W[128][18];
    __shared__ int   baseS[128];

    int tid  = threadIdx.x;
    int wid  = tid >> 6;
    int lane = tid & 63;
    for (int i = tid; i < SACC; i += 128) { accS[0][i] = 0.f; accS[1][i] = 0.f; }

    int a = lane / 6, b = lane - a*6;            // active for lane<36
    int laneoff = a*SA + b*FP;

    int cntT = min(counts[tile], CAP);
    const float4* src = sorted + tile*CAP;

    for (int start = 0; start < cntT; start += 128) {
        int my = start + tid;
        if (my < cntT) {
            float4 s = src[my];
            float fx = floorf(s.x);
            float wx[6]; lag6(s.x - (fx + 0.5f), wx);
            float fy = floorf(s.y);
            float wy[6]; lag6(s.y - (fy + 0.5f), wy);
            float fz = floorf(s.z);
            float wz[6]; lag6(s.z - (fz + 0.5f), wz);
            int lx = wrap120((int)fx) - bx;
            int ly = wrap120((int)fy) - by;
            int lz = wrap120((int)fz) - bz;
            baseS[tid] = lx*SA + ly*FP + lz;
            #pragma unroll
            for (int k=0;k<6;++k) {
                W[tid][k]    = wx[k]*s.w;
                W[tid][6+k]  = wy[k];
                W[tid][12+k] = wz[k];
            }
        }
        __syncthreads();
        int jn = cntT - start - wid*64;
        jn = (jn > 64) ? 64 : jn;
        if (lane < 36) {
            for (int j = 0; j < jn; ++j) {
                int row = wid*64 + j;
                float w2 = W[row][a] * W[row][6+b];
                int ad = baseS[row] + laneoff;
                #pragma unroll
                for (int c=0;c<6;++c)
                    accS[wid][ad + c] += w2 * W[row][12+c];
            }
        }
        __syncthreads();
    }

    for (int i = tid; i < FPCELLS; i += 128) {
        int lx = i / (FP*FP);
        int r  = i - lx*FP*FP;
        int ly = r / FP;
        int lz = r - ly*FP;
        int ai = lx*SA + ly*FP + lz;
        buf[(size_t)tile * FPSTRIDE + i] = accS[0][ai] + accS[1][ai];
    }
}

// ---- radix-8 decimated 120-point DFT inner loop ----
// X[k] = sum_{j<15} Y[k&7][j] * W120^{k*j};  3 strands (j mod 3) for ILP.
#define DFT15_BODY(Yp, kfreq, RE, IM)                                        \
    float w1r, w1i;                                                          \
    __sincosf(-0.052359877559829887f * (float)(kfreq), &w1i, &w1r);          \
    float w2r = w1r*w1r - w1i*w1i, w2i = 2.f*w1r*w1i;                        \
    float w3r = w2r*w1r - w2i*w1i, w3i = w2r*w1i + w2i*w1r;                  \
    float ar=1.f, ai=0.f, br=w1r, bi=w1i, cr=w2r, ci=w2i;                    \
    float r0_=0.f,i0_=0.f,r1_=0.f,i1_=0.f,r2_=0.f,i2_=0.f;                   \
    _Pragma("unroll")                                                        \
    for (int s_=0;s_<5;++s_) {                                               \
        float2 ya = (Yp)[3*s_], yb = (Yp)[3*s_+1], yc = (Yp)[3*s_+2];        \
        r0_ = fmaf(ya.x, ar, fmaf(-ya.y, ai, r0_));                          \
        i0_ = fmaf(ya.x, ai, fmaf( ya.y, ar, i0_));                          \
        r1_ = fmaf(yb.x, br, fmaf(-yb.y, bi, r1_));                          \
        i1_ = fmaf(yb.x, bi, fmaf( yb.y, br, i1_));                          \
        r2_ = fmaf(yc.x, cr, fmaf(-yc.y, ci, r2_));                          \
        i2_ = fmaf(yc.x, ci, fmaf( yc.y, cr, i2_));                          \
        float n_;                                                            \
        n_ = ar*w3r - ai*w3i; ai = ar*w3i + ai*w3r; ar = n_;                 \
        n_ = br*w3r - bi*w3i; bi = br*w3i + bi*w3r; br = n_;                 \
        n_ = cr*w3r - ci*w3i; ci = cr*w3i + ci*w3r; cr = n_;                 \
    }                                                                        \
    float RE = (r0_+r1_)+r2_, IM = (i0_+i1_)+i2_;

// stage 1: halo-gather + rfft along z (radix-8 pre-combine). out C1[x][kz][y].
__global__ void __launch_bounds__(256)
fft_z_kernel(const float* __restrict__ buf,
             float2* __restrict__ C1) {
    int x  = blockIdx.x / 10;
    int y0 = (blockIdx.x - x*10) * YCH;
    __shared__ float  lin[YCH][121];
    __shared__ float2 Ys[YCH][YROW];    // per line: 8 rows * 17 (+1 pad)

    int txA[2], lxA[2];
    int nx = halo_pairs(x, txA, lxA);

    for (int i = threadIdx.x; i < YCH*120; i += 256) {
        int yl = i / 120, z = i - yl*120;
        int tyA[2], lyA[2]; int ny = halo_pairs(y0 + yl, tyA, lyA);
        int tzA[2], lzA[2]; int nz = halo_pairs(z, tzA, lzA);
        float s = 0.f;
        for (int ii=0; ii<nx; ++ii)
            for (int jj=0; jj<ny; ++jj)
                for (int kk=0; kk<nz; ++kk) {
                    int tile = (txA[ii]*NTPD + tyA[jj])*NTPD + tzA[kk];
                    int cell = (lxA[ii]*FP + lyA[jj])*FP + lzA[kk];
                    s += buf[(size_t)tile*FPSTRIDE + cell];
                }
        lin[yl][z] = s;
    }
    __syncthreads();
    // radix-8 combine: z = 15m + j ; Y[r][j] = sum_m x W8^{rm}
    for (int t = threadIdx.x; t < YCH*15; t += 256) {
        int yl = t / 15, j = t - (t/15)*15;
        float2 xin[8], Yo[8];
        #pragma unroll
        for (int m=0;m<8;++m) xin[m] = make_float2(lin[yl][15*m+j], 0.f);
        dft8(xin, Yo);
        #pragma unroll
        for (int r=0;r<8;++r) Ys[yl][r*17+j] = Yo[r];
    }
    __syncthreads();
    for (int o = threadIdx.x; o < YCH*NKZ; o += 256) {
        int kz = o / YCH, yl = o - (o/YCH)*YCH;
        const float2* Yp = &Ys[yl][(kz&7)*17];
        DFT15_BODY(Yp, kz, re, im)
        C1[(x*NKZ + kz)*120 + y0 + yl] = make_float2(re, im);
    }
}

// stage 2: cfft along y (radix-8). block = (4 consecutive x, kz). out C2[kz][ky][x].
__global__ void __launch_bounds__(256)
fft_y_kernel(const float2* __restrict__ C1,
             float2* __restrict__ C2) {
    int xc = blockIdx.x / NKZ;
    int kz = blockIdx.x - xc*NKZ;
    int x0 = xc * XCH;
    __shared__ float2 lin[XCH][121];
    __shared__ float2 Ys[XCH][YROW];
    for (int i = threadIdx.x; i < XCH*120; i += 256) {
        int xo = i / 120, y = i - (i/120)*120;
        lin[xo][y] = C1[((x0+xo)*NKZ + kz)*120 + y];
    }
    __syncthreads();
    for (int t = threadIdx.x; t < XCH*15; t += 256) {
        int xo = t / 15, j = t - (t/15)*15;
        float2 xin[8], Yo[8];
        #pragma unroll
        for (int m=0;m<8;++m) xin[m] = lin[xo][15*m+j];
        dft8(xin, Yo);
        #pragma unroll
        for (int r=0;r<8;++r) Ys[xo][r*17+j] = Yo[r];
    }
    __syncthreads();
    for (int o = threadIdx.x; o < XCH*120; o += 256) {
        int ky = o >> 2, xo = o & 3;
        const float2* Yp = &Ys[xo][(ky&7)*17];
        DFT15_BODY(Yp, ky, re, im)
        C2[(kz*120 + ky)*120 + x0 + xo] = make_float2(re, im);
    }
}

// stage 3: cfft along x (radix-8) + G-weighted energy (slotted atomic).
__global__ void __launch_bounds__(256)
fft_x_energy_kernel(const float2* __restrict__ C2,
                    const float* __restrict__ box,
                    double* __restrict__ ekslots) {
    int kyc = blockIdx.x / NKZ;
    int kz  = blockIdx.x - kyc*NKZ;
    int ky0 = kyc * XCH;
    __shared__ float2 lin[XCH][121];
    __shared__ float2 Ys[XCH][YROW];
    const float2* src = C2 + (kz*120 + ky0)*120;
    for (int i = threadIdx.x; i < XCH*120; i += 256) {
        int kyo = i / 120, xx = i - (i/120)*120;
        lin[kyo][xx] = src[i];
    }
    __syncthreads();
    for (int t = threadIdx.x; t < XCH*15; t += 256) {
        int kyo = t / 15, j = t - (t/15)*15;
        float2 xin[8], Yo[8];
        #pragma unroll
        for (int m=0;m<8;++m) xin[m] = lin[kyo][15*m+j];
        dft8(xin, Yo);
        #pragma unroll
        for (int r=0;r<8;++r) Ys[kyo][r*17+j] = Yo[r];
    }
    __syncthreads();
    float ib[9]; inv3(box, ib);
    const float TWOPI = 6.283185307179586f;
    float wzf = (kz==0 || kz==60) ? 1.0f : 2.0f;
    float contrib = 0.f;
    for (int o = threadIdx.x; o < XCH*120; o += 256) {
        int kyo = o / 120, kx = o - (o/120)*120;
        int ky = ky0 + kyo;
        const float2* Yp = &Ys[kyo][(kx&7)*17];
        DFT15_BODY(Yp, kx, re, im)
        if (!(kx==0 && ky==0 && kz==0)) {
            float mx = (kx < 60) ? (float)kx : (float)(kx - 120);
            float my = (ky < 60) ? (float)ky : (float)(ky - 120);
            float mz = (float)kz;
            float k0 = TWOPI*(mx*ib[0] + my*ib[1] + mz*ib[2]);
            float k1 = TWOPI*(mx*ib[3] + my*ib[4] + mz*ib[5]);
            float k2 = TWOPI*(mx*ib[6] + my*ib[7] + mz*ib[8]);
            float ksq = k0*k0 + k1*k1 + k2*k2;
            float G = 12.566370614359172f * __expf(-0.5f*(float)(ALPHA_C*ALPHA_C)*ksq) / ksq;
            contrib += wzf * G * (re*re + im*im);
        }
    }
    #pragma unroll
    for (int o=32;o>0;o>>=1) contrib += __shfl_down(contrib,o,64);
    __shared__ float sm[4];
    int lane = threadIdx.x & 63, w = threadIdx.x >> 6;
    if (lane==0) sm[w] = contrib;
    __syncthreads();
    if (threadIdx.x==0)
        atomicAdd(&ekslots[(blockIdx.x & (NSLOT-1)) * SLOTSTRIDE],
                  (double)(sm[0]+sm[1]+sm[2]+sm[3]));
}

// 64-lane slot reduction + closed-form corrections
__global__ void finalize_kernel(const double* __restrict__ ekslots,
                                const double* __restrict__ qslots,
                                const double* __restrict__ q2slots,
                                const float* __restrict__ box,
                                float* __restrict__ out) {
    int lane = threadIdx.x;
    double ek  = ekslots[lane*SLOTSTRIDE];
    double sq  = qslots [lane*SLOTSTRIDE];
    double sq2 = q2slots[lane*SLOTSTRIDE];
    #pragma unroll
    for (int o=32;o>0;o>>=1) {
        ek  += __shfl_down(ek,  o, 64);
        sq  += __shfl_down(sq,  o, 64);
        sq2 += __shfl_down(sq2, o, 64);
    }
    if (lane == 0) {
        double a00=box[0],a01=box[1],a02=box[2],a10=box[3],a11=box[4],a12=box[5],a20=box[6],a21=box[7],a22=box[8];
        double det = a00*(a11*a22-a12*a21) - a01*(a10*a22-a12*a20) + a02*(a10*a21-a11*a20);
        double vol = fabs(det);
        double E = ek/(2.0*vol)
                 - 0.5*sqrt(2.0/M_PI)/ALPHA_C * sq2
                 - M_PI*ALPHA_C*ALPHA_C * sq*sq / vol;
        out[0] = (float)E;
    }
}

extern "C" void kernel_launch(void* const* d_in, const int* in_sizes, int n_in,
                              void* d_out, int out_size, void* d_ws, size_t ws_size,
                              hipStream_t stream) {
    const float* coords  = (const float*)d_in[0];
    const float* box     = (const float*)d_in[1];
    const float* charges = (const float*)d_in[2];
    int n = in_sizes[0] / 3;

    char* ws = (char*)d_ws;
    double* ekslots = (double*)(ws + EK_OFF);
    double* qslots  = (double*)(ws + Q_OFF);
    double* q2slots = (double*)(ws + Q2_OFF);
    float*  buf     = (float*) (ws + BUF_OFF);
    float2* C1      = (float2*)(ws + C1_OFF);
    float2* C2      = (float2*)(ws + C2_OFF);
    int* counts     = (int*)(ws + COUNTS_OFF);
    float4* sorted  = (float4*)(ws + SORTED_OFF);

    int gA = (n + 255)/256;
    init_kernel<<<1, 1024, 0, stream>>>(counts, ekslots);
    scatter_q_kernel<<<gA, 256, 0, stream>>>(coords, box, charges, counts, sorted, qslots, q2slots, n);
    spread_tile_kernel<<<NTILE, 128, 0, stream>>>(sorted, counts, buf);
    fft_z_kernel<<<120*10, 256, 0, stream>>>(buf, C1);
    fft_y_kernel<<<30*NKZ, 256, 0, stream>>>(C1, C2);
    fft_x_energy_kernel<<<NKZ*30, 256, 0, stream>>>(C2, box, ekslots);
    finalize_kernel<<<1, 64, 0, stream>>>(ekslots, qslots, q2slots, box, (float*)d_out);
}